// Round 2
// baseline (2447.001 us; speedup 1.0000x reference)
//
#include <hip/hip_runtime.h>
#include <stdint.h>
#include <math.h>

#define DIM 3072
#define SEQ 4096
#define NH 24
#define HD 128
#define MLP 9216
#define FUSED 27648   // 3*DIM + 2*MLP
#define SD FUSED      // row stride of qkv_mlp buffer
#define K2 12288      // fused output-GEMM K (DIM + MLP)

typedef __attribute__((ext_vector_type(8))) short short8;
typedef __attribute__((ext_vector_type(4))) float f32x4;

__device__ __forceinline__ float bf2f(uint16_t b){ uint32_t x = ((uint32_t)b)<<16; return __builtin_bit_cast(float,x); }
__device__ __forceinline__ uint16_t f2bf(float f){
  uint32_t x = __builtin_bit_cast(uint32_t,f);
  x += 0x7fffu + ((x>>16)&1u);
  return (uint16_t)(x>>16);
}
__device__ __forceinline__ void gl_lds16(const void* g, void* l){
  __builtin_amdgcn_global_load_lds((const __attribute__((address_space(1))) void*)g,
                                   (__attribute__((address_space(3))) void*)l, 16, 0, 0);
}

// ---------------- transpose + cast fp32[K,N] -> bf16[N,:] at dst[n*dstStride + k] ----------------
__global__ __launch_bounds__(256) void castT_kernel(const float* __restrict__ src,
                                                    uint16_t* __restrict__ dst,
                                                    int K, int N, int dstStride){
  __shared__ float tile[32][33];
  int t = threadIdx.x;
  int n0 = blockIdx.x<<5, k0 = blockIdx.y<<5;
  int r = t>>3, c4 = (t&7)<<2;
  float4 v = *(const float4*)&src[(size_t)(k0+r)*N + n0 + c4];
  tile[r][c4] = v.x; tile[r][c4+1] = v.y; tile[r][c4+2] = v.z; tile[r][c4+3] = v.w;
  __syncthreads();
  int n = t>>3, kc = (t&7)<<2;
  ushort4 o;
  o.x = f2bf(tile[kc  ][n]);
  o.y = f2bf(tile[kc+1][n]);
  o.z = f2bf(tile[kc+2][n]);
  o.w = f2bf(tile[kc+3][n]);
  *(ushort4*)&dst[(size_t)(n0+n)*dstStride + k0 + kc] = o;
}

// ---------------- LayerNorm + modulation -> bf16 h ----------------
__global__ __launch_bounds__(256) void ln_mod_kernel(const float* __restrict__ x,
                                                     const float* __restrict__ temb,
                                                     uint16_t* __restrict__ h){
  int s = blockIdx.x;
  int t = threadIdx.x;
  const float4* row = (const float4*)(x + (size_t)s*DIM);
  float4 v[3];
  float sum=0.f, ss=0.f;
  #pragma unroll
  for (int i=0;i<3;i++){
    v[i] = row[t + i*256];
    sum += v[i].x+v[i].y+v[i].z+v[i].w;
    ss  += v[i].x*v[i].x + v[i].y*v[i].y + v[i].z*v[i].z + v[i].w*v[i].w;
  }
  #pragma unroll
  for (int off=32; off; off>>=1){ sum += __shfl_xor(sum, off, 64); ss += __shfl_xor(ss, off, 64); }
  __shared__ float red[8];
  int lane = t&63, w = t>>6;
  if (lane==0){ red[w]=sum; red[w+4]=ss; }
  __syncthreads();
  sum = red[0]+red[1]+red[2]+red[3];
  ss  = red[4]+red[5]+red[6]+red[7];
  float mu = sum*(1.f/DIM);
  float var = ss*(1.f/DIM) - mu*mu;
  float rs = rsqrtf(var + 1e-6f);
  uint16_t* hrow = h + (size_t)s*DIM;
  #pragma unroll
  for (int i=0;i<3;i++){
    int c = (t + i*256)*4;
    float4 sc = *(const float4*)&temb[DIM + c];
    float4 sh = *(const float4*)&temb[c];
    ushort4 o;
    o.x = f2bf((v[i].x - mu)*rs*(1.f+sc.x) + sh.x);
    o.y = f2bf((v[i].y - mu)*rs*(1.f+sc.y) + sh.y);
    o.z = f2bf((v[i].z - mu)*rs*(1.f+sc.z) + sh.z);
    o.w = f2bf((v[i].w - mu)*rs*(1.f+sc.w) + sh.w);
    *(ushort4*)&hrow[c] = o;
  }
}

// ---------------- 256x256-tile pipelined 8-phase GEMM: C[M,N] = A[M,K] * BT[N,K]^T ----------------
// 512 threads = 8 waves (2M x 4N), BK=64, per-wave C = 128x64 (acc[8][4]).
// LDS 128 KiB: A,B each 2-buf x 2-half x [128][64] bf16, granule-XOR swizzled.
// ds_reads are software-pipelined ONE WINDOW AHEAD of their consuming MFMA phase:
//   p0 window: read p1's A frags | stage (T+1).A0 | bar | [auto lgkmcnt(4)] MFMA p0 | bar
//   p1 window: read p2's A frags | stage (T+1).A1 | ...
//   p2 window: read p3's A frags | stage (T+2).B0 | ...
//   p3 window: stage (T+2).B1 | bar | MFMA p3 | vmcnt(4) | TAIL: read T+1's B frags (8)
//              + T+1's p0 A frags (4) from the nxt buffers | bar
// The tail reads are legal exactly after p3's vmcnt(4) (it drains A(T+1)+B(T+1));
// they drain in the barrier/issue slack before T+1.p0's MFMA. Compiler inserts
// counted lgkmcnt (the 4 newest in-flight reads excluded) — no blanket lgkmcnt(0).
#define STAGE_HT(SRC, LDSB, KOFF) do{ \
    gl_lds16((SRC) + (KOFF), (LDSB) + (size_t)t*8); \
    gl_lds16((SRC) + r64K + (KOFF), (LDSB) + (size_t)(t+512)*8); \
  }while(0)

#define PH_READ4(d0,d1,d2,d3, BASE, MIA, MIB) \
    d0 = *(const short8*)&(BASE)[(MIA)*1024 + pk0]; \
    d1 = *(const short8*)&(BASE)[(MIA)*1024 + pk1]; \
    d2 = *(const short8*)&(BASE)[(MIB)*1024 + pk0]; \
    d3 = *(const short8*)&(BASE)[(MIB)*1024 + pk1];

#define PH_MFMA4(s0,s1,s2,s3, MI0, MI1) \
    _Pragma("unroll") \
    for (int ni=0; ni<4; ni++){ \
      acc[MI0][ni] = __builtin_amdgcn_mfma_f32_16x16x32_bf16(s0, bfr[ni][0], acc[MI0][ni], 0,0,0); \
      acc[MI1][ni] = __builtin_amdgcn_mfma_f32_16x16x32_bf16(s2, bfr[ni][0], acc[MI1][ni], 0,0,0); \
      acc[MI0][ni] = __builtin_amdgcn_mfma_f32_16x16x32_bf16(s1, bfr[ni][1], acc[MI0][ni], 0,0,0); \
      acc[MI1][ni] = __builtin_amdgcn_mfma_f32_16x16x32_bf16(s3, bfr[ni][1], acc[MI1][ni], 0,0,0); \
    }

#define PH_COMMIT \
    __builtin_amdgcn_sched_barrier(0); \
    __builtin_amdgcn_s_barrier(); \
    __builtin_amdgcn_s_setprio(1);

#define PH_CLOSE \
    __builtin_amdgcn_s_setprio(0); \
    __builtin_amdgcn_sched_barrier(0); \
    __builtin_amdgcn_s_barrier();

template<bool OUT_BF16, bool FINAL>
__global__ __launch_bounds__(512,2) void gemm256_kernel(const uint16_t* __restrict__ A,
                                                        const uint16_t* __restrict__ BT,
                                                        void* __restrict__ Cout,
                                                        const float* __restrict__ resid,
                                                        const float* __restrict__ temb,
                                                        int M, int N, int K){
  __shared__ alignas(16) uint16_t As[2][2][128*64];
  __shared__ alignas(16) uint16_t Bs[2][2][128*64];
  const int t = threadIdx.x, lane = t&63, w = t>>6;
  // XCD-bijective swizzle (grid % 8 == 0), then n-major / m-inner for L2 reuse
  const int G = gridDim.x, cpx = G>>3;
  const int b = blockIdx.x;
  const int b2 = (b&7)*cpx + (b>>3);
  const int mt = M>>8;
  const int n_t = b2/mt, m_t = b2 - n_t*mt;
  const size_t m0 = (size_t)m_t<<8, n0 = (size_t)n_t<<8;
  const int wm = (w>>2)<<7, wn = (w&3)<<6;
  const int lr = lane&15, q4 = lane>>4;
  // staging: thread t covers chunks c=t and c=t+512 of each 128x64 half-tile.
  // chunk c -> LDS byte c*16 (linear dest, required by global_load_lds); source is
  // pre-swizzled: holds global (row r=c>>3, granule g=(c&7)^(r&7)). The matching
  // XOR on the read side spreads a 16-lane column read over 8 granules (2-way = free).
  const int r0 = t>>3;
  const int g0 = (t&7) ^ (r0&7);
  const uint16_t* Asrc = A  + (m0 + r0)*(size_t)K + g0*8;
  const uint16_t* Bsrc = BT + (n0 + r0)*(size_t)K + g0*8;
  const size_t r64K = (size_t)64*K, r128K = (size_t)128*K;
  // frag-read bases (E = buffer 0, O = buffer 1; 16384 elements = 32 KiB apart)
  const int halfA = w>>2, halfB = (w&3)>>1, rbB = wn&64;
  const uint16_t* ArdE = &As[0][halfA][0] + lr*64;
  const uint16_t* BrdE = &Bs[0][halfB][0] + (rbB+lr)*64;
  const uint16_t* ArdO = ArdE + 16384;
  const uint16_t* BrdO = BrdE + 16384;
  const int x7 = lr&7;
  const int pk0 = (q4^x7)<<3, pk1 = ((q4|4)^x7)<<3;
  // prologue: T0 fully (8 loads) + T1.B halves (4 loads); vmcnt(4) drains T0 only
  STAGE_HT(Bsrc, &Bs[0][0][0], (size_t)0);
  STAGE_HT(Bsrc, &Bs[0][1][0], r128K);
  STAGE_HT(Asrc, &As[0][0][0], (size_t)0);
  STAGE_HT(Asrc, &As[0][1][0], r128K);
  STAGE_HT(Bsrc, &Bs[1][0][0], (size_t)64);
  STAGE_HT(Bsrc, &Bs[1][1][0], r128K + 64);
  asm volatile("s_waitcnt vmcnt(4)" ::: "memory");
  __builtin_amdgcn_s_barrier();
  // initial register frags: B(T0) all 8, A(T0) p0 pair (mi0,1)
  short8 pa0,pa1,pa2,pa3, qa0,qa1,qa2,qa3;
  short8 bfr[4][2];
  PH_READ4(pa0,pa1,pa2,pa3, ArdE, 0, 1);
  #pragma unroll
  for (int ni=0; ni<4; ni++){
    bfr[ni][0] = *(const short8*)&BrdE[ni*1024 + pk0];
    bfr[ni][1] = *(const short8*)&BrdE[ni*1024 + pk1];
  }
  f32x4 acc[8][4] = {};
  const int NT = K>>6;
  for (int T=0; T<NT; ++T){
    const uint16_t* AbC = (T&1) ? ArdO : ArdE;   // tile T read base
    const uint16_t* AbN = (T&1) ? ArdE : ArdO;   // tile T+1 read base (tail)
    const uint16_t* BbN = (T&1) ? BrdE : BrdO;
    uint16_t* AsN0 = &As[(T&1)^1][0][0];
    uint16_t* AsN1 = &As[(T&1)^1][1][0];
    uint16_t* BsC0 = &Bs[T&1][0][0];
    uint16_t* BsC1 = &Bs[T&1][1][0];
    const bool stA = (T+1<NT), stB = (T+2<NT);
    const size_t kA = (size_t)(T+1)<<6, kB = (size_t)(T+2)<<6;
    // p0: compute mi0,1 | prefetch mi2,3 | stage A0(T+1)
    PH_READ4(qa0,qa1,qa2,qa3, AbC, 2, 3);
    if (stA){ STAGE_HT(Asrc, AsN0, kA); }
    PH_COMMIT
    PH_MFMA4(pa0,pa1,pa2,pa3, 0, 1)
    PH_CLOSE
    // p1: compute mi2,3 | prefetch mi4,5 | stage A1(T+1)
    PH_READ4(pa0,pa1,pa2,pa3, AbC, 4, 5);
    if (stA){ STAGE_HT(Asrc, AsN1, kA + r128K); }
    PH_COMMIT
    PH_MFMA4(qa0,qa1,qa2,qa3, 2, 3)
    PH_CLOSE
    // p2: compute mi4,5 | prefetch mi6,7 | stage B0(T+2)
    PH_READ4(qa0,qa1,qa2,qa3, AbC, 6, 7);
    if (stB){ STAGE_HT(Bsrc, BsC0, kB); }
    PH_COMMIT
    PH_MFMA4(pa0,pa1,pa2,pa3, 4, 5)
    PH_CLOSE
    // p3: compute mi6,7 | stage B1(T+2) | tail: vmcnt + next-tile frag reads
    if (stB){ STAGE_HT(Bsrc, BsC1, kB + r128K); }
    PH_COMMIT
    PH_MFMA4(qa0,qa1,qa2,qa3, 6, 7)
    __builtin_amdgcn_s_setprio(0);
    if (T+1 < NT){
      if (stB){ asm volatile("s_waitcnt vmcnt(4)" ::: "memory"); }
      else    { asm volatile("s_waitcnt vmcnt(0)" ::: "memory"); }
      PH_READ4(pa0,pa1,pa2,pa3, AbN, 0, 1);
      #pragma unroll
      for (int ni=0; ni<4; ni++){
        bfr[ni][0] = *(const short8*)&BbN[ni*1024 + pk0];
        bfr[ni][1] = *(const short8*)&BbN[ni*1024 + pk1];
      }
    }
    __builtin_amdgcn_sched_barrier(0);
    __builtin_amdgcn_s_barrier();
  }
  // epilogue: C/D frag mapping col=lane&15, row=(lane>>4)*4+r (same as verified 128^2 kernel)
  #pragma unroll
  for (int mi=0; mi<8; mi++){
    #pragma unroll
    for (int ni=0; ni<4; ni++){
      const size_t col = n0 + wn + ni*16 + lr;
      const float gate = FINAL ? temb[2*DIM + col] : 0.f;
      #pragma unroll
      for (int r=0; r<4; r++){
        const size_t row = m0 + wm + mi*16 + (q4<<2) + r;
        const size_t idx = row*(size_t)N + col;
        float vv = acc[mi][ni][r];
        if (FINAL) vv = resid[idx] + gate*vv;
        if (OUT_BF16) ((uint16_t*)Cout)[idx] = f2bf(vv);
        else          ((float*)Cout)[idx] = vv;
      }
    }
  }
}

// ---------------- per-head RMSNorm + RoPE on q,k (in place) ----------------
__global__ __launch_bounds__(256) void qk_rope_kernel(uint16_t* __restrict__ qkv,
                                                      const float* __restrict__ cosb,
                                                      const float* __restrict__ sinb,
                                                      const float* __restrict__ wq,
                                                      const float* __restrict__ wk){
  int t = threadIdx.x, lane = t&63, w = t>>6;
  int pair = blockIdx.x*4 + w;
  int s = pair/24, hh = pair - s*24;
  int d0 = lane*2;
  float c0 = cosb[s*HD + d0], c1 = cosb[s*HD + d0+1];
  float sn0 = sinb[s*HD + d0], sn1 = sinb[s*HD + d0+1];
  #pragma unroll
  for (int which=0; which<2; ++which){
    uint16_t* p = qkv + (size_t)s*SD + which*DIM + hh*HD + d0;
    const float* ww = which ? wk : wq;
    uint32_t u = *(const uint32_t*)p;
    float x0 = bf2f((uint16_t)(u&0xffffu)), x1 = bf2f((uint16_t)(u>>16));
    float ssum = x0*x0 + x1*x1;
    #pragma unroll
    for (int off=32; off; off>>=1) ssum += __shfl_xor(ssum, off, 64);
    float r = rsqrtf(ssum*(1.f/HD) + 1e-6f);
    float xn0 = x0*r*ww[d0], xn1 = x1*r*ww[d0+1];
    float y0 = xn0*c0 - xn1*sn0;
    float y1 = xn1*c1 + xn0*sn1;
    *(uint32_t*)p = (uint32_t)f2bf(y0) | ((uint32_t)f2bf(y1)<<16);
  }
}

// ---------------- flash attention (out has row stride K2, cols 0..DIM-1) ----------------
__global__ __launch_bounds__(256) void attn_kernel(const uint16_t* __restrict__ qkv,
                                                   uint16_t* __restrict__ out){
  __shared__ alignas(16) uint16_t QP[64*128];   // Q staging, then per-wave P (swizzled)
  __shared__ alignas(16) uint16_t Ks[64*128];   // [key][d], d-granule swizzled by key&15
  __shared__ alignas(16) uint16_t Vt[128*64];   // [d][key], key-granule swizzled by (d>>1)&7
  int t = threadIdx.x, lane = t&63, w = t>>6;
  int q0 = blockIdx.x<<6, h = blockIdx.y;
  int lr = lane&15, q4 = lane>>4, lk = q4<<3;
  const uint16_t* qb = qkv + (size_t)q0*SD + h*HD;
  #pragma unroll
  for (int i=0;i<4;i++){
    int c = t + i*256;
    gl_lds16((const char*)(qb + (size_t)(c>>4)*SD) + ((c&15)<<4), (char*)QP + c*16);
  }
  __syncthreads();
  short8 qf[4];
  #pragma unroll
  for (int kc=0;kc<4;kc++) qf[kc] = *(const short8*)&QP[(w*16+lr)*128 + kc*32 + lk];
  __syncthreads();   // QP now reusable as P scratch
  float m_i[4] = {-3.0e38f,-3.0e38f,-3.0e38f,-3.0e38f};
  float l_i[4] = {0.f,0.f,0.f,0.f};
  f32x4 o[8] = {};
  const uint16_t* kb = qkv + (size_t)DIM + h*HD;
  const uint16_t* vb = qkv + (size_t)(2*DIM) + h*HD;
  uint16_t* Pw = QP + w*(16*64);
  const float scale = 0.08838834764831845f;
  for (int kt=0; kt<64; ++kt){
    const uint16_t* kbt = kb + (size_t)(kt<<6)*SD;
    const uint16_t* vbt = vb + (size_t)(kt<<6)*SD;
    __syncthreads();
    #pragma unroll
    for (int i=0;i<4;i++){          // K tile, swizzled
      int c = t + i*256;
      int row = c>>4, gd = c&15;
      uint4 vv = *(const uint4*)(kbt + (size_t)row*SD + gd*8);
      *(uint4*)&Ks[row*128 + ((gd ^ (row&15))<<3)] = vv;
    }
    #pragma unroll
    for (int i=0;i<8;i++){          // V tile, transposed + swizzled
      int idx = t + i*256;
      int rp = idx>>6;
      int k0 = rp<<1, d0 = lane<<1;
      uint32_t u0 = *(const uint32_t*)(vbt + (size_t)k0*SD + d0);
      uint32_t u1 = *(const uint32_t*)(vbt + (size_t)(k0+1)*SD + d0);
      int pos = (((rp>>2) ^ (lane&7))<<3) + (k0&7);
      *(uint32_t*)&Vt[(d0<<6) + pos]     = (u0&0xffffu) | (u1<<16);
      *(uint32_t*)&Vt[((d0+1)<<6) + pos] = (u0>>16) | (u1&0xffff0000u);
    }
    __syncthreads();
    f32x4 sa[4];
    #pragma unroll
    for (int nk=0;nk<4;nk++){
      sa[nk] = (f32x4){0.f,0.f,0.f,0.f};
      #pragma unroll
      for (int kc=0;kc<4;kc++){
        short8 kf = *(const short8*)&Ks[(nk*16+lr)*128 + (((kc*4+q4) ^ lr)<<3)];
        sa[nk] = __builtin_amdgcn_mfma_f32_16x16x32_bf16(qf[kc], kf, sa[nk], 0,0,0);
      }
      sa[nk] *= scale;
    }
    float alpha[4], psum[4];
    #pragma unroll
    for (int r=0;r<4;r++){
      float mx = fmaxf(fmaxf(sa[0][r], sa[1][r]), fmaxf(sa[2][r], sa[3][r]));
      mx = fmaxf(mx, __shfl_xor(mx, 1, 64));
      mx = fmaxf(mx, __shfl_xor(mx, 2, 64));
      mx = fmaxf(mx, __shfl_xor(mx, 4, 64));
      mx = fmaxf(mx, __shfl_xor(mx, 8, 64));
      float mn = fmaxf(m_i[r], mx);
      alpha[r] = __expf(m_i[r] - mn);
      m_i[r] = mn;
      psum[r] = 0.f;
    }
    int prow = q4<<2;
    #pragma unroll
    for (int nk=0;nk<4;nk++){
      #pragma unroll
      for (int r=0;r<4;r++){
        float p = __expf(sa[nk][r] - m_i[r]);
        psum[r] += p;
        int key = nk*16 + lr;
        Pw[(prow+r)*64 + ((((key>>3) ^ (prow+r))&7)<<3) + (key&7)] = f2bf(p);
      }
    }
    #pragma unroll
    for (int r=0;r<4;r++){
      float ps = psum[r];
      ps += __shfl_xor(ps, 1, 64);
      ps += __shfl_xor(ps, 2, 64);
      ps += __shfl_xor(ps, 4, 64);
      ps += __shfl_xor(ps, 8, 64);
      l_i[r] = l_i[r]*alpha[r] + ps;
    }
    #pragma unroll
    for (int nd=0;nd<8;nd++){
      f32x4 t4 = o[nd];
      t4[0]*=alpha[0]; t4[1]*=alpha[1]; t4[2]*=alpha[2]; t4[3]*=alpha[3];
      o[nd]=t4;
    }
    #pragma unroll
    for (int kc=0;kc<2;kc++){
      short8 pf = *(const short8*)&Pw[lr*64 + ((((kc*4+q4) ^ lr)&7)<<3)];
      #pragma unroll
      for (int nd=0;nd<8;nd++){
        int d = nd*16 + lr;
        short8 vf = *(const short8*)&Vt[(d<<6) + ((((kc*4+q4) ^ ((lr>>1)&7)))<<3)];
        o[nd] = __builtin_amdgcn_mfma_f32_16x16x32_bf16(pf, vf, o[nd], 0,0,0);
      }
    }
  }
  uint16_t* ob = out + (size_t)(q0 + w*16)*K2 + h*HD;
  #pragma unroll
  for (int r=0;r<4;r++){
    float inv = 1.f/l_i[r];
    #pragma unroll
    for (int nd=0;nd<8;nd++)
      ob[(size_t)(q4*4 + r)*K2 + nd*16 + lr] = f2bf(o[nd][r]*inv);
  }
}

// ---------------- SwiGLU (out has row stride K2, at col offset DIM) ----------------
__global__ __launch_bounds__(256) void swiglu_kernel(const uint16_t* __restrict__ qkv,
                                                     uint16_t* __restrict__ mlp){
  size_t idx = ((size_t)blockIdx.x*256 + threadIdx.x)*4;
  size_t s = idx/MLP, j = idx - s*MLP;
  const uint16_t* pa = qkv + s*SD + 3*DIM + j;
  const uint16_t* pb = pa + MLP;
  ushort4 ua = *(const ushort4*)pa, ub = *(const ushort4*)pb;
  ushort4 o;
  float a, b;
  a = bf2f(ua.x); b = bf2f(ub.x); o.x = f2bf(a*b/(1.f+__expf(-a)));
  a = bf2f(ua.y); b = bf2f(ub.y); o.y = f2bf(a*b/(1.f+__expf(-a)));
  a = bf2f(ua.z); b = bf2f(ub.z); o.z = f2bf(a*b/(1.f+__expf(-a)));
  a = bf2f(ua.w); b = bf2f(ub.w); o.w = f2bf(a*b/(1.f+__expf(-a)));
  *(ushort4*)(mlp + s*K2 + j) = o;
}

extern "C" void kernel_launch(void* const* d_in, const int* in_sizes, int n_in,
                              void* d_out, int out_size, void* d_ws, size_t ws_size,
                              hipStream_t stream){
  (void)in_sizes; (void)n_in; (void)out_size;
  const float* hs   = (const float*)d_in[0];
  const float* temb = (const float*)d_in[1];
  const float* rcos = (const float*)d_in[2];
  const float* rsin = (const float*)d_in[3];
  const float* w1   = (const float*)d_in[4];
  const float* wa   = (const float*)d_in[5];
  const float* wm   = (const float*)d_in[6];
  const float* nqw  = (const float*)d_in[7];
  const float* nkw  = (const float*)d_in[8];

  char* ws = (char*)d_ws;
  const size_t off_w1T  = 0;               // 27648x3072 bf16 = 169,869,312
  const size_t off_woT  = 169869312ULL;    // 3072x12288 bf16 =  75,497,472
  const size_t off_h    = 245366784ULL;    // 4096x3072  bf16 =  25,165,824
  const size_t off_qkv  = 270532608ULL;    // 4096x27648 bf16 = 226,492,416
  const size_t off_ap   = 497025024ULL;    // 4096x12288 bf16 = 100,663,296
  const size_t needed   = 597688320ULL;
  if (ws_size < needed) return;

  uint16_t* w1T  = (uint16_t*)(ws + off_w1T);
  uint16_t* woT  = (uint16_t*)(ws + off_woT);
  uint16_t* hbuf = (uint16_t*)(ws + off_h);
  uint16_t* qkv  = (uint16_t*)(ws + off_qkv);
  uint16_t* ap   = (uint16_t*)(ws + off_ap);   // [attn | swiglu] fused A'

  castT_kernel<<<dim3(FUSED/32, DIM/32), 256, 0, stream>>>(w1, w1T, DIM, FUSED, DIM);
  castT_kernel<<<dim3(DIM/32,  DIM/32),  256, 0, stream>>>(wa, woT, DIM, DIM, K2);
  castT_kernel<<<dim3(DIM/32,  MLP/32),  256, 0, stream>>>(wm, woT + DIM, MLP, DIM, K2);
  ln_mod_kernel<<<SEQ, 256, 0, stream>>>(hs, temb, hbuf);
  gemm256_kernel<true,false><<<(SEQ/256)*(FUSED/256), 512, 0, stream>>>(hbuf, w1T, qkv, nullptr, nullptr, SEQ, FUSED, DIM);
  qk_rope_kernel<<<SEQ*NH/4, 256, 0, stream>>>(qkv, rcos, rsin, nqw, nkw);
  attn_kernel<<<dim3(SEQ/64, NH), 256, 0, stream>>>(qkv, ap);
  swiglu_kernel<<<(SEQ*(size_t)MLP/4)/256, 256, 0, stream>>>(qkv, ap + DIM);
  gemm256_kernel<false,true><<<(SEQ/256)*(DIM/256), 512, 0, stream>>>(ap, woT, d_out, hs, temb, SEQ, DIM, K2);
}

// Round 3
// 2425.524 us; speedup vs baseline: 1.0089x; 1.0089x over previous
//
#include <hip/hip_runtime.h>
#include <stdint.h>
#include <math.h>

#define DIM 3072
#define SEQ 4096
#define NH 24
#define HD 128
#define MLP 9216
#define FUSED 27648   // 3*DIM + 2*MLP
#define SD FUSED      // row stride of qkv_mlp buffer
#define K2 12288      // fused output-GEMM K (DIM + MLP)

typedef __attribute__((ext_vector_type(8))) short short8;
typedef __attribute__((ext_vector_type(4))) float f32x4;

__device__ __forceinline__ float bf2f(uint16_t b){ uint32_t x = ((uint32_t)b)<<16; return __builtin_bit_cast(float,x); }
__device__ __forceinline__ uint16_t f2bf(float f){
  uint32_t x = __builtin_bit_cast(uint32_t,f);
  x += 0x7fffu + ((x>>16)&1u);
  return (uint16_t)(x>>16);
}
__device__ __forceinline__ void gl_lds16(const void* g, void* l){
  __builtin_amdgcn_global_load_lds((const __attribute__((address_space(1))) void*)g,
                                   (__attribute__((address_space(3))) void*)l, 16, 0, 0);
}

// ---------------- transpose + cast fp32[K,N] -> bf16[N,:] at dst[n*dstStride + k] ----------------
__global__ __launch_bounds__(256) void castT_kernel(const float* __restrict__ src,
                                                    uint16_t* __restrict__ dst,
                                                    int K, int N, int dstStride){
  __shared__ float tile[32][33];
  int t = threadIdx.x;
  int n0 = blockIdx.x<<5, k0 = blockIdx.y<<5;
  int r = t>>3, c4 = (t&7)<<2;
  float4 v = *(const float4*)&src[(size_t)(k0+r)*N + n0 + c4];
  tile[r][c4] = v.x; tile[r][c4+1] = v.y; tile[r][c4+2] = v.z; tile[r][c4+3] = v.w;
  __syncthreads();
  int n = t>>3, kc = (t&7)<<2;
  ushort4 o;
  o.x = f2bf(tile[kc  ][n]);
  o.y = f2bf(tile[kc+1][n]);
  o.z = f2bf(tile[kc+2][n]);
  o.w = f2bf(tile[kc+3][n]);
  *(ushort4*)&dst[(size_t)(n0+n)*dstStride + k0 + kc] = o;
}

// ---------------- LayerNorm + modulation -> bf16 h ----------------
__global__ __launch_bounds__(256) void ln_mod_kernel(const float* __restrict__ x,
                                                     const float* __restrict__ temb,
                                                     uint16_t* __restrict__ h){
  int s = blockIdx.x;
  int t = threadIdx.x;
  const float4* row = (const float4*)(x + (size_t)s*DIM);
  float4 v[3];
  float sum=0.f, ss=0.f;
  #pragma unroll
  for (int i=0;i<3;i++){
    v[i] = row[t + i*256];
    sum += v[i].x+v[i].y+v[i].z+v[i].w;
    ss  += v[i].x*v[i].x + v[i].y*v[i].y + v[i].z*v[i].z + v[i].w*v[i].w;
  }
  #pragma unroll
  for (int off=32; off; off>>=1){ sum += __shfl_xor(sum, off, 64); ss += __shfl_xor(ss, off, 64); }
  __shared__ float red[8];
  int lane = t&63, w = t>>6;
  if (lane==0){ red[w]=sum; red[w+4]=ss; }
  __syncthreads();
  sum = red[0]+red[1]+red[2]+red[3];
  ss  = red[4]+red[5]+red[6]+red[7];
  float mu = sum*(1.f/DIM);
  float var = ss*(1.f/DIM) - mu*mu;
  float rs = rsqrtf(var + 1e-6f);
  uint16_t* hrow = h + (size_t)s*DIM;
  #pragma unroll
  for (int i=0;i<3;i++){
    int c = (t + i*256)*4;
    float4 sc = *(const float4*)&temb[DIM + c];
    float4 sh = *(const float4*)&temb[c];
    ushort4 o;
    o.x = f2bf((v[i].x - mu)*rs*(1.f+sc.x) + sh.x);
    o.y = f2bf((v[i].y - mu)*rs*(1.f+sc.y) + sh.y);
    o.z = f2bf((v[i].z - mu)*rs*(1.f+sc.z) + sh.z);
    o.w = f2bf((v[i].w - mu)*rs*(1.f+sc.w) + sh.w);
    *(ushort4*)&hrow[c] = o;
  }
}

// ---------------- 256x256-tile 1-barrier/K-tile GEMM: C[M,N] = A[M,K] * BT[N,K]^T ----------------
// 512 threads = 8 waves (2M x 4N), BK=64, per-wave C = 128x64 (acc[8][4]).
// LDS 128 KiB: A,B double-buffered [128][64] bf16 halves, granule-XOR swizzled.
// ONE s_barrier per K-tile. All intra-tile ordering is per-wave program order:
//   head: ds_read B frags(8) + A mi0,1(4) from [cur]; issue 8 global_load_lds
//         staging tile T+1 into [nxt]  (HBM latency hides under ~2500cy tile body)
//   p0..p3: 16-MFMA clusters, next phase's A-frag reads interleaved by compiler
//   end: lgkmcnt(0) (own reads returned) + vmcnt(0) (own stages landed, issued
//        ~2300cy earlier => ~free) + s_barrier.
// Cross-wave safety: a wave crosses the barrier only after its [cur] reads RETURNED
// and its [nxt] stage writes LANDED; tile T+1 overwrites [cur] and reads [nxt], so
// no overwrite can clobber an in-flight read and no read can see partial stages.
#define STAGE_HT(SRC, LDSB, KOFF) do{ \
    gl_lds16((SRC) + (KOFF), (LDSB) + (size_t)t*8); \
    gl_lds16((SRC) + r64K + (KOFF), (LDSB) + (size_t)(t+512)*8); \
  }while(0)

#define PH_READ4(d0,d1,d2,d3, BASE, MIA, MIB) \
    d0 = *(const short8*)&(BASE)[(MIA)*1024 + pk0]; \
    d1 = *(const short8*)&(BASE)[(MIA)*1024 + pk1]; \
    d2 = *(const short8*)&(BASE)[(MIB)*1024 + pk0]; \
    d3 = *(const short8*)&(BASE)[(MIB)*1024 + pk1];

#define PH_MFMA4(s0,s1,s2,s3, MI0, MI1) \
    __builtin_amdgcn_s_setprio(1); \
    _Pragma("unroll") \
    for (int ni=0; ni<4; ni++){ \
      acc[MI0][ni] = __builtin_amdgcn_mfma_f32_16x16x32_bf16(s0, bfr[ni][0], acc[MI0][ni], 0,0,0); \
      acc[MI1][ni] = __builtin_amdgcn_mfma_f32_16x16x32_bf16(s2, bfr[ni][0], acc[MI1][ni], 0,0,0); \
      acc[MI0][ni] = __builtin_amdgcn_mfma_f32_16x16x32_bf16(s1, bfr[ni][1], acc[MI0][ni], 0,0,0); \
      acc[MI1][ni] = __builtin_amdgcn_mfma_f32_16x16x32_bf16(s3, bfr[ni][1], acc[MI1][ni], 0,0,0); \
    } \
    __builtin_amdgcn_s_setprio(0);

template<bool OUT_BF16, bool FINAL>
__global__ __launch_bounds__(512,2) void gemm256_kernel(const uint16_t* __restrict__ A,
                                                        const uint16_t* __restrict__ BT,
                                                        void* __restrict__ Cout,
                                                        const float* __restrict__ resid,
                                                        const float* __restrict__ temb,
                                                        int M, int N, int K){
  __shared__ alignas(16) uint16_t As[2][2][128*64];
  __shared__ alignas(16) uint16_t Bs[2][2][128*64];
  const int t = threadIdx.x, lane = t&63, w = t>>6;
  // XCD-bijective swizzle (grid % 8 == 0), then n-major / m-inner for L2 reuse
  const int G = gridDim.x, cpx = G>>3;
  const int b = blockIdx.x;
  const int b2 = (b&7)*cpx + (b>>3);
  const int mt = M>>8;
  const int n_t = b2/mt, m_t = b2 - n_t*mt;
  const size_t m0 = (size_t)m_t<<8, n0 = (size_t)n_t<<8;
  const int wm = (w>>2)<<7, wn = (w&3)<<6;
  const int lr = lane&15, q4 = lane>>4;
  // staging: thread t covers chunks c=t and c=t+512 of each 128x64 half-tile.
  // chunk c -> LDS byte c*16 (linear dest, required by global_load_lds); source is
  // pre-swizzled: holds global (row r=c>>3, granule g=(c&7)^(r&7)). The matching
  // XOR on the read side spreads a 16-lane column read over 8 granules (2-way = free).
  const int r0 = t>>3;
  const int g0 = (t&7) ^ (r0&7);
  const uint16_t* Asrc = A  + (m0 + r0)*(size_t)K + g0*8;
  const uint16_t* Bsrc = BT + (n0 + r0)*(size_t)K + g0*8;
  const size_t r64K = (size_t)64*K, r128K = (size_t)128*K;
  // frag-read bases (E = buffer 0, O = buffer 1; 16384 elements = 32 KiB apart)
  const int halfA = w>>2, halfB = (w&3)>>1, rbB = wn&64;
  const uint16_t* ArdE = &As[0][halfA][0] + lr*64;
  const uint16_t* BrdE = &Bs[0][halfB][0] + (rbB+lr)*64;
  const uint16_t* ArdO = ArdE + 16384;
  const uint16_t* BrdO = BrdE + 16384;
  const int x7 = lr&7;
  const int pk0 = (q4^x7)<<3, pk1 = ((q4|4)<<3)^(x7<<3);
  // prologue: stage T0 into buffer 0, full drain
  STAGE_HT(Bsrc, &Bs[0][0][0], (size_t)0);
  STAGE_HT(Bsrc, &Bs[0][1][0], r128K);
  STAGE_HT(Asrc, &As[0][0][0], (size_t)0);
  STAGE_HT(Asrc, &As[0][1][0], r128K);
  asm volatile("s_waitcnt vmcnt(0)" ::: "memory");
  __builtin_amdgcn_s_barrier();
  __builtin_amdgcn_sched_barrier(0);
  f32x4 acc[8][4] = {};
  const int NT = K>>6;
  for (int T=0; T<NT; ++T){
    const uint16_t* Ab = (T&1) ? ArdO : ArdE;
    const uint16_t* Bb = (T&1) ? BrdO : BrdE;
    const int nx = (T&1)^1;
    const bool st = (T+1<NT);
    const size_t kN = (size_t)(T+1)<<6;
    // head: all B frags + p0's A frags from [cur]
    short8 bfr[4][2];
    #pragma unroll
    for (int ni=0; ni<4; ni++){
      bfr[ni][0] = *(const short8*)&Bb[ni*1024 + pk0];
      bfr[ni][1] = *(const short8*)&Bb[ni*1024 + pk1];
    }
    short8 pa0,pa1,pa2,pa3, qa0,qa1,qa2,qa3;
    PH_READ4(pa0,pa1,pa2,pa3, Ab, 0, 1);
    // stage next tile early so vmcnt(0) at tile end is free
    if (st){
      STAGE_HT(Asrc, &As[nx][0][0], kN);
      STAGE_HT(Asrc, &As[nx][1][0], kN + r128K);
      STAGE_HT(Bsrc, &Bs[nx][0][0], kN);
      STAGE_HT(Bsrc, &Bs[nx][1][0], kN + r128K);
    }
    // p0..p3: MFMA clusters with next phase's reads left free for the scheduler
    PH_READ4(qa0,qa1,qa2,qa3, Ab, 2, 3);
    PH_MFMA4(pa0,pa1,pa2,pa3, 0, 1)
    PH_READ4(pa0,pa1,pa2,pa3, Ab, 4, 5);
    PH_MFMA4(qa0,qa1,qa2,qa3, 2, 3)
    PH_READ4(qa0,qa1,qa2,qa3, Ab, 6, 7);
    PH_MFMA4(pa0,pa1,pa2,pa3, 4, 5)
    PH_MFMA4(qa0,qa1,qa2,qa3, 6, 7)
    // tile end: own reads returned + own stages landed, then single barrier
    asm volatile("s_waitcnt vmcnt(0) lgkmcnt(0)" ::: "memory");
    __builtin_amdgcn_s_barrier();
    __builtin_amdgcn_sched_barrier(0);
  }
  // epilogue: C/D frag mapping col=lane&15, row=(lane>>4)*4+r (same as verified 128^2 kernel)
  #pragma unroll
  for (int mi=0; mi<8; mi++){
    #pragma unroll
    for (int ni=0; ni<4; ni++){
      const size_t col = n0 + wn + ni*16 + lr;
      const float gate = FINAL ? temb[2*DIM + col] : 0.f;
      #pragma unroll
      for (int r=0; r<4; r++){
        const size_t row = m0 + wm + mi*16 + (q4<<2) + r;
        const size_t idx = row*(size_t)N + col;
        float vv = acc[mi][ni][r];
        if (FINAL) vv = resid[idx] + gate*vv;
        if (OUT_BF16) ((uint16_t*)Cout)[idx] = f2bf(vv);
        else          ((float*)Cout)[idx] = vv;
      }
    }
  }
}

// ---------------- per-head RMSNorm + RoPE on q,k (in place) ----------------
__global__ __launch_bounds__(256) void qk_rope_kernel(uint16_t* __restrict__ qkv,
                                                      const float* __restrict__ cosb,
                                                      const float* __restrict__ sinb,
                                                      const float* __restrict__ wq,
                                                      const float* __restrict__ wk){
  int t = threadIdx.x, lane = t&63, w = t>>6;
  int pair = blockIdx.x*4 + w;
  int s = pair/24, hh = pair - s*24;
  int d0 = lane*2;
  float c0 = cosb[s*HD + d0], c1 = cosb[s*HD + d0+1];
  float sn0 = sinb[s*HD + d0], sn1 = sinb[s*HD + d0+1];
  #pragma unroll
  for (int which=0; which<2; ++which){
    uint16_t* p = qkv + (size_t)s*SD + which*DIM + hh*HD + d0;
    const float* ww = which ? wk : wq;
    uint32_t u = *(const uint32_t*)p;
    float x0 = bf2f((uint16_t)(u&0xffffu)), x1 = bf2f((uint16_t)(u>>16));
    float ssum = x0*x0 + x1*x1;
    #pragma unroll
    for (int off=32; off; off>>=1) ssum += __shfl_xor(ssum, off, 64);
    float r = rsqrtf(ssum*(1.f/HD) + 1e-6f);
    float xn0 = x0*r*ww[d0], xn1 = x1*r*ww[d0+1];
    float y0 = xn0*c0 - xn1*sn0;
    float y1 = xn1*c1 + xn0*sn1;
    *(uint32_t*)p = (uint32_t)f2bf(y0) | ((uint32_t)f2bf(y1)<<16);
  }
}

// ---------------- flash attention (out has row stride K2, cols 0..DIM-1) ----------------
__global__ __launch_bounds__(256) void attn_kernel(const uint16_t* __restrict__ qkv,
                                                   uint16_t* __restrict__ out){
  __shared__ alignas(16) uint16_t QP[64*128];   // Q staging, then per-wave P (swizzled)
  __shared__ alignas(16) uint16_t Ks[64*128];   // [key][d], d-granule swizzled by key&15
  __shared__ alignas(16) uint16_t Vt[128*64];   // [d][key], key-granule swizzled by (d>>1)&7
  int t = threadIdx.x, lane = t&63, w = t>>6;
  int q0 = blockIdx.x<<6, h = blockIdx.y;
  int lr = lane&15, q4 = lane>>4, lk = q4<<3;
  const uint16_t* qb = qkv + (size_t)q0*SD + h*HD;
  #pragma unroll
  for (int i=0;i<4;i++){
    int c = t + i*256;
    gl_lds16((const char*)(qb + (size_t)(c>>4)*SD) + ((c&15)<<4), (char*)QP + c*16);
  }
  __syncthreads();
  short8 qf[4];
  #pragma unroll
  for (int kc=0;kc<4;kc++) qf[kc] = *(const short8*)&QP[(w*16+lr)*128 + kc*32 + lk];
  __syncthreads();   // QP now reusable as P scratch
  float m_i[4] = {-3.0e38f,-3.0e38f,-3.0e38f,-3.0e38f};
  float l_i[4] = {0.f,0.f,0.f,0.f};
  f32x4 o[8] = {};
  const uint16_t* kb = qkv + (size_t)DIM + h*HD;
  const uint16_t* vb = qkv + (size_t)(2*DIM) + h*HD;
  uint16_t* Pw = QP + w*(16*64);
  const float scale = 0.08838834764831845f;
  for (int kt=0; kt<64; ++kt){
    const uint16_t* kbt = kb + (size_t)(kt<<6)*SD;
    const uint16_t* vbt = vb + (size_t)(kt<<6)*SD;
    __syncthreads();
    #pragma unroll
    for (int i=0;i<4;i++){          // K tile, swizzled
      int c = t + i*256;
      int row = c>>4, gd = c&15;
      uint4 vv = *(const uint4*)(kbt + (size_t)row*SD + gd*8);
      *(uint4*)&Ks[row*128 + ((gd ^ (row&15))<<3)] = vv;
    }
    #pragma unroll
    for (int i=0;i<8;i++){          // V tile, transposed + swizzled
      int idx = t + i*256;
      int rp = idx>>6;
      int k0 = rp<<1, d0 = lane<<1;
      uint32_t u0 = *(const uint32_t*)(vbt + (size_t)k0*SD + d0);
      uint32_t u1 = *(const uint32_t*)(vbt + (size_t)(k0+1)*SD + d0);
      int pos = (((rp>>2) ^ (lane&7))<<3) + (k0&7);
      *(uint32_t*)&Vt[(d0<<6) + pos]     = (u0&0xffffu) | (u1<<16);
      *(uint32_t*)&Vt[((d0+1)<<6) + pos] = (u0>>16) | (u1&0xffff0000u);
    }
    __syncthreads();
    f32x4 sa[4];
    #pragma unroll
    for (int nk=0;nk<4;nk++){
      sa[nk] = (f32x4){0.f,0.f,0.f,0.f};
      #pragma unroll
      for (int kc=0;kc<4;kc++){
        short8 kf = *(const short8*)&Ks[(nk*16+lr)*128 + (((kc*4+q4) ^ lr)<<3)];
        sa[nk] = __builtin_amdgcn_mfma_f32_16x16x32_bf16(qf[kc], kf, sa[nk], 0,0,0);
      }
      sa[nk] *= scale;
    }
    float alpha[4], psum[4];
    #pragma unroll
    for (int r=0;r<4;r++){
      float mx = fmaxf(fmaxf(sa[0][r], sa[1][r]), fmaxf(sa[2][r], sa[3][r]));
      mx = fmaxf(mx, __shfl_xor(mx, 1, 64));
      mx = fmaxf(mx, __shfl_xor(mx, 2, 64));
      mx = fmaxf(mx, __shfl_xor(mx, 4, 64));
      mx = fmaxf(mx, __shfl_xor(mx, 8, 64));
      float mn = fmaxf(m_i[r], mx);
      alpha[r] = __expf(m_i[r] - mn);
      m_i[r] = mn;
      psum[r] = 0.f;
    }
    int prow = q4<<2;
    #pragma unroll
    for (int nk=0;nk<4;nk++){
      #pragma unroll
      for (int r=0;r<4;r++){
        float p = __expf(sa[nk][r] - m_i[r]);
        psum[r] += p;
        int key = nk*16 + lr;
        Pw[(prow+r)*64 + ((((key>>3) ^ (prow+r))&7)<<3) + (key&7)] = f2bf(p);
      }
    }
    #pragma unroll
    for (int r=0;r<4;r++){
      float ps = psum[r];
      ps += __shfl_xor(ps, 1, 64);
      ps += __shfl_xor(ps, 2, 64);
      ps += __shfl_xor(ps, 4, 64);
      ps += __shfl_xor(ps, 8, 64);
      l_i[r] = l_i[r]*alpha[r] + ps;
    }
    #pragma unroll
    for (int nd=0;nd<8;nd++){
      f32x4 t4 = o[nd];
      t4[0]*=alpha[0]; t4[1]*=alpha[1]; t4[2]*=alpha[2]; t4[3]*=alpha[3];
      o[nd]=t4;
    }
    #pragma unroll
    for (int kc=0;kc<2;kc++){
      short8 pf = *(const short8*)&Pw[lr*64 + ((((kc*4+q4) ^ lr)&7)<<3)];
      #pragma unroll
      for (int nd=0;nd<8;nd++){
        int d = nd*16 + lr;
        short8 vf = *(const short8*)&Vt[(d<<6) + ((((kc*4+q4) ^ ((lr>>1)&7)))<<3)];
        o[nd] = __builtin_amdgcn_mfma_f32_16x16x32_bf16(pf, vf, o[nd], 0,0,0);
      }
    }
  }
  uint16_t* ob = out + (size_t)(q0 + w*16)*K2 + h*HD;
  #pragma unroll
  for (int r=0;r<4;r++){
    float inv = 1.f/l_i[r];
    #pragma unroll
    for (int nd=0;nd<8;nd++)
      ob[(size_t)(q4*4 + r)*K2 + nd*16 + lr] = f2bf(o[nd][r]*inv);
  }
}

// ---------------- SwiGLU (out has row stride K2, at col offset DIM) ----------------
__global__ __launch_bounds__(256) void swiglu_kernel(const uint16_t* __restrict__ qkv,
                                                     uint16_t* __restrict__ mlp){
  size_t idx = ((size_t)blockIdx.x*256 + threadIdx.x)*4;
  size_t s = idx/MLP, j = idx - s*MLP;
  const uint16_t* pa = qkv + s*SD + 3*DIM + j;
  const uint16_t* pb = pa + MLP;
  ushort4 ua = *(const ushort4*)pa, ub = *(const ushort4*)pb;
  ushort4 o;
  float a, b;
  a = bf2f(ua.x); b = bf2f(ub.x); o.x = f2bf(a*b/(1.f+__expf(-a)));
  a = bf2f(ua.y); b = bf2f(ub.y); o.y = f2bf(a*b/(1.f+__expf(-a)));
  a = bf2f(ua.z); b = bf2f(ub.z); o.z = f2bf(a*b/(1.f+__expf(-a)));
  a = bf2f(ua.w); b = bf2f(ub.w); o.w = f2bf(a*b/(1.f+__expf(-a)));
  *(ushort4*)(mlp + s*K2 + j) = o;
}

extern "C" void kernel_launch(void* const* d_in, const int* in_sizes, int n_in,
                              void* d_out, int out_size, void* d_ws, size_t ws_size,
                              hipStream_t stream){
  (void)in_sizes; (void)n_in; (void)out_size;
  const float* hs   = (const float*)d_in[0];
  const float* temb = (const float*)d_in[1];
  const float* rcos = (const float*)d_in[2];
  const float* rsin = (const float*)d_in[3];
  const float* w1   = (const float*)d_in[4];
  const float* wa   = (const float*)d_in[5];
  const float* wm   = (const float*)d_in[6];
  const float* nqw  = (const float*)d_in[7];
  const float* nkw  = (const float*)d_in[8];

  char* ws = (char*)d_ws;
  const size_t off_w1T  = 0;               // 27648x3072 bf16 = 169,869,312
  const size_t off_woT  = 169869312ULL;    // 3072x12288 bf16 =  75,497,472
  const size_t off_h    = 245366784ULL;    // 4096x3072  bf16 =  25,165,824
  const size_t off_qkv  = 270532608ULL;    // 4096x27648 bf16 = 226,492,416
  const size_t off_ap   = 497025024ULL;    // 4096x12288 bf16 = 100,663,296
  const size_t needed   = 597688320ULL;
  if (ws_size < needed) return;

  uint16_t* w1T  = (uint16_t*)(ws + off_w1T);
  uint16_t* woT  = (uint16_t*)(ws + off_woT);
  uint16_t* hbuf = (uint16_t*)(ws + off_h);
  uint16_t* qkv  = (uint16_t*)(ws + off_qkv);
  uint16_t* ap   = (uint16_t*)(ws + off_ap);   // [attn | swiglu] fused A'

  castT_kernel<<<dim3(FUSED/32, DIM/32), 256, 0, stream>>>(w1, w1T, DIM, FUSED, DIM);
  castT_kernel<<<dim3(DIM/32,  DIM/32),  256, 0, stream>>>(wa, woT, DIM, DIM, K2);
  castT_kernel<<<dim3(DIM/32,  MLP/32),  256, 0, stream>>>(wm, woT + DIM, MLP, DIM, K2);
  ln_mod_kernel<<<SEQ, 256, 0, stream>>>(hs, temb, hbuf);
  gemm256_kernel<true,false><<<(SEQ/256)*(FUSED/256), 512, 0, stream>>>(hbuf, w1T, qkv, nullptr, nullptr, SEQ, FUSED, DIM);
  qk_rope_kernel<<<SEQ*NH/4, 256, 0, stream>>>(qkv, rcos, rsin, nqw, nkw);
  attn_kernel<<<dim3(SEQ/64, NH), 256, 0, stream>>>(qkv, ap);
  swiglu_kernel<<<(SEQ*(size_t)MLP/4)/256, 256, 0, stream>>>(qkv, ap + DIM);
  gemm256_kernel<false,true><<<(SEQ/256)*(DIM/256), 512, 0, stream>>>(ap, woT, d_out, hs, temb, SEQ, DIM, K2);
}

// Round 4
// 2288.574 us; speedup vs baseline: 1.0692x; 1.0598x over previous
//
#include <hip/hip_runtime.h>
#include <stdint.h>
#include <math.h>

#define DIM 3072
#define SEQ 4096
#define NH 24
#define HD 128
#define MLP 9216
#define FUSED 27648   // 3*DIM + 2*MLP
#define SD FUSED      // row stride of qkv_mlp buffer
#define K2 12288      // fused output-GEMM K (DIM + MLP)

typedef __attribute__((ext_vector_type(8))) short short8;
typedef __attribute__((ext_vector_type(4))) float f32x4;

__device__ __forceinline__ float bf2f(uint16_t b){ uint32_t x = ((uint32_t)b)<<16; return __builtin_bit_cast(float,x); }
__device__ __forceinline__ uint16_t f2bf(float f){
  uint32_t x = __builtin_bit_cast(uint32_t,f);
  x += 0x7fffu + ((x>>16)&1u);
  return (uint16_t)(x>>16);
}
__device__ __forceinline__ void gl_lds16(const void* g, void* l){
  __builtin_amdgcn_global_load_lds((const __attribute__((address_space(1))) void*)g,
                                   (__attribute__((address_space(3))) void*)l, 16, 0, 0);
}

// ---------------- transpose + cast fp32[K,N] -> bf16[N,:] at dst[n*dstStride + k] ----------------
__global__ __launch_bounds__(256) void castT_kernel(const float* __restrict__ src,
                                                    uint16_t* __restrict__ dst,
                                                    int K, int N, int dstStride){
  __shared__ float tile[32][33];
  int t = threadIdx.x;
  int n0 = blockIdx.x<<5, k0 = blockIdx.y<<5;
  int r = t>>3, c4 = (t&7)<<2;
  float4 v = *(const float4*)&src[(size_t)(k0+r)*N + n0 + c4];
  tile[r][c4] = v.x; tile[r][c4+1] = v.y; tile[r][c4+2] = v.z; tile[r][c4+3] = v.w;
  __syncthreads();
  int n = t>>3, kc = (t&7)<<2;
  ushort4 o;
  o.x = f2bf(tile[kc  ][n]);
  o.y = f2bf(tile[kc+1][n]);
  o.z = f2bf(tile[kc+2][n]);
  o.w = f2bf(tile[kc+3][n]);
  *(ushort4*)&dst[(size_t)(n0+n)*dstStride + k0 + kc] = o;
}

// ---------------- LayerNorm + modulation -> bf16 h ----------------
__global__ __launch_bounds__(256) void ln_mod_kernel(const float* __restrict__ x,
                                                     const float* __restrict__ temb,
                                                     uint16_t* __restrict__ h){
  int s = blockIdx.x;
  int t = threadIdx.x;
  const float4* row = (const float4*)(x + (size_t)s*DIM);
  float4 v[3];
  float sum=0.f, ss=0.f;
  #pragma unroll
  for (int i=0;i<3;i++){
    v[i] = row[t + i*256];
    sum += v[i].x+v[i].y+v[i].z+v[i].w;
    ss  += v[i].x*v[i].x + v[i].y*v[i].y + v[i].z*v[i].z + v[i].w*v[i].w;
  }
  #pragma unroll
  for (int off=32; off; off>>=1){ sum += __shfl_xor(sum, off, 64); ss += __shfl_xor(ss, off, 64); }
  __shared__ float red[8];
  int lane = t&63, w = t>>6;
  if (lane==0){ red[w]=sum; red[w+4]=ss; }
  __syncthreads();
  sum = red[0]+red[1]+red[2]+red[3];
  ss  = red[4]+red[5]+red[6]+red[7];
  float mu = sum*(1.f/DIM);
  float var = ss*(1.f/DIM) - mu*mu;
  float rs = rsqrtf(var + 1e-6f);
  uint16_t* hrow = h + (size_t)s*DIM;
  #pragma unroll
  for (int i=0;i<3;i++){
    int c = (t + i*256)*4;
    float4 sc = *(const float4*)&temb[DIM + c];
    float4 sh = *(const float4*)&temb[c];
    ushort4 o;
    o.x = f2bf((v[i].x - mu)*rs*(1.f+sc.x) + sh.x);
    o.y = f2bf((v[i].y - mu)*rs*(1.f+sc.y) + sh.y);
    o.z = f2bf((v[i].z - mu)*rs*(1.f+sc.z) + sh.z);
    o.w = f2bf((v[i].w - mu)*rs*(1.f+sc.w) + sh.w);
    *(ushort4*)&hrow[c] = o;
  }
}

// ---------------- 256x256-tile 8-phase GEMM (round-1 verified best: 766us GEMM1) ----------------
#define STAGE_HT(SRC, LDSB, KOFF) do{ \
    gl_lds16((SRC) + (KOFF), (LDSB) + (size_t)t*8); \
    gl_lds16((SRC) + r64K + (KOFF), (LDSB) + (size_t)(t+512)*8); \
  }while(0)

#define GPHASE(MI0, MI1, STG, WAITV) do{ \
    short8 a00 = *(const short8*)&Ab[(MI0)*1024 + pk0]; \
    short8 a01 = *(const short8*)&Ab[(MI0)*1024 + pk1]; \
    short8 a10 = *(const short8*)&Ab[(MI1)*1024 + pk0]; \
    short8 a11 = *(const short8*)&Ab[(MI1)*1024 + pk1]; \
    STG; \
    __builtin_amdgcn_s_barrier(); \
    asm volatile("s_waitcnt lgkmcnt(0)" ::: "memory"); \
    __builtin_amdgcn_s_setprio(1); \
    _Pragma("unroll") \
    for (int ni=0; ni<4; ni++){ \
      acc[MI0][ni] = __builtin_amdgcn_mfma_f32_16x16x32_bf16(a00, bfr[ni][0], acc[MI0][ni], 0,0,0); \
      acc[MI1][ni] = __builtin_amdgcn_mfma_f32_16x16x32_bf16(a10, bfr[ni][0], acc[MI1][ni], 0,0,0); \
      acc[MI0][ni] = __builtin_amdgcn_mfma_f32_16x16x32_bf16(a01, bfr[ni][1], acc[MI0][ni], 0,0,0); \
      acc[MI1][ni] = __builtin_amdgcn_mfma_f32_16x16x32_bf16(a11, bfr[ni][1], acc[MI1][ni], 0,0,0); \
    } \
    __builtin_amdgcn_s_setprio(0); \
    WAITV \
    __builtin_amdgcn_s_barrier(); \
  }while(0)

template<bool OUT_BF16, bool FINAL>
__global__ __launch_bounds__(512,2) void gemm256_kernel(const uint16_t* __restrict__ A,
                                                        const uint16_t* __restrict__ BT,
                                                        void* __restrict__ Cout,
                                                        const float* __restrict__ resid,
                                                        const float* __restrict__ temb,
                                                        int M, int N, int K){
  __shared__ alignas(16) uint16_t As[2][2][128*64];
  __shared__ alignas(16) uint16_t Bs[2][2][128*64];
  const int t = threadIdx.x, lane = t&63, w = t>>6;
  const int G = gridDim.x, cpx = G>>3;
  const int b = blockIdx.x;
  const int b2 = (b&7)*cpx + (b>>3);
  const int mt = M>>8;
  const int n_t = b2/mt, m_t = b2 - n_t*mt;
  const size_t m0 = (size_t)m_t<<8, n0 = (size_t)n_t<<8;
  const int wm = (w>>2)<<7, wn = (w&3)<<6;
  const int lr = lane&15, q4 = lane>>4;
  const int r0 = t>>3;
  const int g0 = (t&7) ^ (r0&7);
  const uint16_t* Asrc = A  + (m0 + r0)*(size_t)K + g0*8;
  const uint16_t* Bsrc = BT + (n0 + r0)*(size_t)K + g0*8;
  const size_t r64K = (size_t)64*K, r128K = (size_t)128*K;
  const int halfA = w>>2, halfB = (w&3)>>1, rbB = wn&64;
  const uint16_t* ArdBase = &As[0][halfA][0] + lr*64;
  const uint16_t* BrdBase = &Bs[0][halfB][0] + (rbB+lr)*64;
  const int x7 = lr&7;
  const int pk0 = (q4^x7)<<3, pk1 = ((q4|4)^x7)<<3;
  // prologue: T0 fully (8 loads) + T1.B halves (4 loads); vmcnt(4) drains T0 only
  STAGE_HT(Bsrc, &Bs[0][0][0], (size_t)0);
  STAGE_HT(Bsrc, &Bs[0][1][0], r128K);
  STAGE_HT(Asrc, &As[0][0][0], (size_t)0);
  STAGE_HT(Asrc, &As[0][1][0], r128K);
  STAGE_HT(Bsrc, &Bs[1][0][0], (size_t)64);
  STAGE_HT(Bsrc, &Bs[1][1][0], r128K + 64);
  asm volatile("s_waitcnt vmcnt(4)" ::: "memory");
  __builtin_amdgcn_s_barrier();
  f32x4 acc[8][4] = {};
  const int NT = K>>6;
  for (int T=0; T<NT; ++T){
    const int cur = T&1, nxt = cur^1;
    const uint16_t* Ab = ArdBase + (cur<<14);
    const uint16_t* Bb = BrdBase + (cur<<14);
    uint16_t* AsN0 = &As[nxt][0][0]; uint16_t* AsN1 = &As[nxt][1][0];
    uint16_t* BsC0 = &Bs[cur][0][0]; uint16_t* BsC1 = &Bs[cur][1][0];
    const bool stA = (T+1<NT), stB = (T+2<NT);
    const size_t kA = (size_t)(T+1)<<6, kB = (size_t)(T+2)<<6;
    short8 bfr[4][2];
    #pragma unroll
    for (int ni=0; ni<4; ni++){
      bfr[ni][0] = *(const short8*)&Bb[ni*1024 + pk0];
      bfr[ni][1] = *(const short8*)&Bb[ni*1024 + pk1];
    }
    GPHASE(0,1, if(stA){ STAGE_HT(Asrc, AsN0, kA); }, ;);
    GPHASE(2,3, if(stA){ STAGE_HT(Asrc, AsN1, kA + r128K); }, ;);
    GPHASE(4,5, if(stB){ STAGE_HT(Bsrc, BsC0, kB); }, ;);
    GPHASE(6,7, if(stB){ STAGE_HT(Bsrc, BsC1, kB + r128K); },
           if(stB){ asm volatile("s_waitcnt vmcnt(4)" ::: "memory"); }
           else   { asm volatile("s_waitcnt vmcnt(0)" ::: "memory"); });
  }
  #pragma unroll
  for (int mi=0; mi<8; mi++){
    #pragma unroll
    for (int ni=0; ni<4; ni++){
      const size_t col = n0 + wn + ni*16 + lr;
      const float gate = FINAL ? temb[2*DIM + col] : 0.f;
      #pragma unroll
      for (int r=0; r<4; r++){
        const size_t row = m0 + wm + mi*16 + (q4<<2) + r;
        const size_t idx = row*(size_t)N + col;
        float vv = acc[mi][ni][r];
        if (FINAL) vv = resid[idx] + gate*vv;
        if (OUT_BF16) ((uint16_t*)Cout)[idx] = f2bf(vv);
        else          ((float*)Cout)[idx] = vv;
      }
    }
  }
}

// ---------------- per-head RMSNorm + RoPE on q,k (in place) ----------------
__global__ __launch_bounds__(256) void qk_rope_kernel(uint16_t* __restrict__ qkv,
                                                      const float* __restrict__ cosb,
                                                      const float* __restrict__ sinb,
                                                      const float* __restrict__ wq,
                                                      const float* __restrict__ wk){
  int t = threadIdx.x, lane = t&63, w = t>>6;
  int pair = blockIdx.x*4 + w;
  int s = pair/24, hh = pair - s*24;
  int d0 = lane*2;
  float c0 = cosb[s*HD + d0], c1 = cosb[s*HD + d0+1];
  float sn0 = sinb[s*HD + d0], sn1 = sinb[s*HD + d0+1];
  #pragma unroll
  for (int which=0; which<2; ++which){
    uint16_t* p = qkv + (size_t)s*SD + which*DIM + hh*HD + d0;
    const float* ww = which ? wk : wq;
    uint32_t u = *(const uint32_t*)p;
    float x0 = bf2f((uint16_t)(u&0xffffu)), x1 = bf2f((uint16_t)(u>>16));
    float ssum = x0*x0 + x1*x1;
    #pragma unroll
    for (int off=32; off; off>>=1) ssum += __shfl_xor(ssum, off, 64);
    float r = rsqrtf(ssum*(1.f/HD) + 1e-6f);
    float xn0 = x0*r*ww[d0], xn1 = x1*r*ww[d0+1];
    float y0 = xn0*c0 - xn1*sn0;
    float y1 = xn1*c1 + xn0*sn1;
    *(uint32_t*)p = (uint32_t)f2bf(y0) | ((uint32_t)f2bf(y1)<<16);
  }
}

// ---------------- flash attention (out has row stride K2, cols 0..DIM-1) ----------------
// Swapped QK^T: S^T = mfma(K,Q) puts all 64 scores of query q=lr in lane-local regs
// (C layout: col=lane&15 -> q, row=(lane>>4)*4+r (+16*nk) -> key). Softmax row-reduce
// becomes in-lane chain + 2 shfl_xor (vs 32 shfl). P written as 4x 8B packed stores.
// T13 defer-max: skip o-rescale when __all(pmax <= m+8). K staged via global_load_lds
// with pre-swizzled SOURCE (LDS content identical to old write-side swizzle).
__global__ __launch_bounds__(256) void attn_kernel(const uint16_t* __restrict__ qkv,
                                                   uint16_t* __restrict__ out){
  __shared__ alignas(16) uint16_t QP[64*128];   // Q staging, then per-wave P (swizzled)
  __shared__ alignas(16) uint16_t Ks[64*128];   // [key][d], d-granule swizzled by key&15
  __shared__ alignas(16) uint16_t Vt[128*64];   // [d][key], key-granule swizzled by (d>>1)&7
  int t = threadIdx.x, lane = t&63, w = t>>6;
  int q0 = blockIdx.x<<6, h = blockIdx.y;
  int lr = lane&15, q4 = lane>>4, lk = q4<<3;
  const uint16_t* qb = qkv + (size_t)q0*SD + h*HD;
  #pragma unroll
  for (int i=0;i<4;i++){
    int c = t + i*256;
    gl_lds16((const char*)(qb + (size_t)(c>>4)*SD) + ((c&15)<<4), (char*)QP + c*16);
  }
  __syncthreads();
  short8 qf[4];
  #pragma unroll
  for (int kc=0;kc<4;kc++) qf[kc] = *(const short8*)&QP[(w*16+lr)*128 + kc*32 + lk];
  __syncthreads();   // QP now reusable as P scratch
  float m_q = -3.0e38f, l_q = 0.f;   // running max/denom for query q=lr (replicated x4)
  f32x4 o[8] = {};
  const uint16_t* kb = qkv + (size_t)DIM + h*HD;
  const uint16_t* vb = qkv + (size_t)(2*DIM) + h*HD;
  uint16_t* Pw = QP + w*(16*64);
  const float scale = 0.08838834764831845f;
  for (int kt=0; kt<64; ++kt){
    const uint16_t* kbt = kb + (size_t)(kt<<6)*SD;
    const uint16_t* vbt = vb + (size_t)(kt<<6)*SD;
    __syncthreads();
    #pragma unroll
    for (int i=0;i<4;i++){          // K tile: pre-swizzled source, linear LDS dest
      int c = t + i*256;
      int row = c>>4, gd = c&15;
      gl_lds16((const char*)(kbt + (size_t)row*SD) + (((gd ^ (row&15))&15)<<4),
               (char*)Ks + c*16);
    }
    #pragma unroll
    for (int i=0;i<8;i++){          // V tile, transposed + swizzled (reg-staged)
      int idx = t + i*256;
      int rp = idx>>6;
      int k0 = rp<<1, d0 = lane<<1;
      uint32_t u0 = *(const uint32_t*)(vbt + (size_t)k0*SD + d0);
      uint32_t u1 = *(const uint32_t*)(vbt + (size_t)(k0+1)*SD + d0);
      int pos = (((rp>>2) ^ (lane&7))<<3) + (k0&7);
      *(uint32_t*)&Vt[(d0<<6) + pos]     = (u0&0xffffu) | (u1<<16);
      *(uint32_t*)&Vt[((d0+1)<<6) + pos] = (u0>>16) | (u1&0xffff0000u);
    }
    __syncthreads();
    // QK^T swapped: ta[nk][r] = S[q=lr][key = nk*16 + q4*4 + r] * scale
    f32x4 ta[4];
    __builtin_amdgcn_s_setprio(1);
    #pragma unroll
    for (int nk=0;nk<4;nk++){
      ta[nk] = (f32x4){0.f,0.f,0.f,0.f};
      #pragma unroll
      for (int kc=0;kc<4;kc++){
        short8 kf = *(const short8*)&Ks[(nk*16+lr)*128 + (((kc*4+q4) ^ lr)<<3)];
        ta[nk] = __builtin_amdgcn_mfma_f32_16x16x32_bf16(kf, qf[kc], ta[nk], 0,0,0);
      }
      ta[nk] *= scale;
    }
    __builtin_amdgcn_s_setprio(0);
    // in-lane max over 16 + 2 shfl across q4 groups
    float mx01 = fmaxf(fmaxf(ta[0][0],ta[0][1]), fmaxf(ta[0][2],ta[0][3]));
    float mx23 = fmaxf(fmaxf(ta[1][0],ta[1][1]), fmaxf(ta[1][2],ta[1][3]));
    float mx45 = fmaxf(fmaxf(ta[2][0],ta[2][1]), fmaxf(ta[2][2],ta[2][3]));
    float mx67 = fmaxf(fmaxf(ta[3][0],ta[3][1]), fmaxf(ta[3][2],ta[3][3]));
    float pmax = fmaxf(fmaxf(mx01,mx23), fmaxf(mx45,mx67));
    pmax = fmaxf(pmax, __shfl_xor(pmax, 16, 64));
    pmax = fmaxf(pmax, __shfl_xor(pmax, 32, 64));
    // defer-max: keep old m if no significant growth (wave-uniform)
    int skip = __all(pmax <= m_q + 8.f);
    float alpha_q = 1.f;
    if (!skip){
      float mnew = fmaxf(m_q, pmax);
      alpha_q = __expf(m_q - mnew);
      m_q = mnew;
    }
    float psum = 0.f;
    #pragma unroll
    for (int nk=0;nk<4;nk++){
      float p0 = __expf(ta[nk][0] - m_q);
      float p1 = __expf(ta[nk][1] - m_q);
      float p2 = __expf(ta[nk][2] - m_q);
      float p3 = __expf(ta[nk][3] - m_q);
      psum += (p0+p1)+(p2+p3);
      uint32_t lo = (uint32_t)f2bf(p0) | ((uint32_t)f2bf(p1)<<16);
      uint32_t hi = (uint32_t)f2bf(p2) | ((uint32_t)f2bf(p3)<<16);
      int k0 = nk*16 + (q4<<2);
      uint2 pk; pk.x = lo; pk.y = hi;
      *(uint2*)&Pw[lr*64 + ((((k0>>3) ^ lr)&7)<<3) + (k0&7)] = pk;
    }
    psum += __shfl_xor(psum, 16, 64);
    psum += __shfl_xor(psum, 32, 64);
    l_q = l_q*alpha_q + psum;
    if (!skip){
      float aR0 = __shfl(alpha_q, (q4<<2)+0, 64);
      float aR1 = __shfl(alpha_q, (q4<<2)+1, 64);
      float aR2 = __shfl(alpha_q, (q4<<2)+2, 64);
      float aR3 = __shfl(alpha_q, (q4<<2)+3, 64);
      #pragma unroll
      for (int nd=0;nd<8;nd++){
        f32x4 t4 = o[nd];
        t4[0]*=aR0; t4[1]*=aR1; t4[2]*=aR2; t4[3]*=aR3;
        o[nd]=t4;
      }
    }
    __builtin_amdgcn_s_setprio(1);
    #pragma unroll
    for (int kc=0;kc<2;kc++){
      short8 pf = *(const short8*)&Pw[lr*64 + ((((kc*4+q4) ^ lr)&7)<<3)];
      #pragma unroll
      for (int nd=0;nd<8;nd++){
        int d = nd*16 + lr;
        short8 vf = *(const short8*)&Vt[(d<<6) + ((((kc*4+q4) ^ ((lr>>1)&7)))<<3)];
        o[nd] = __builtin_amdgcn_mfma_f32_16x16x32_bf16(pf, vf, o[nd], 0,0,0);
      }
    }
    __builtin_amdgcn_s_setprio(0);
  }
  float linv0 = 1.f/__shfl(l_q, (q4<<2)+0, 64);
  float linv1 = 1.f/__shfl(l_q, (q4<<2)+1, 64);
  float linv2 = 1.f/__shfl(l_q, (q4<<2)+2, 64);
  float linv3 = 1.f/__shfl(l_q, (q4<<2)+3, 64);
  uint16_t* ob = out + (size_t)(q0 + w*16)*K2 + h*HD;
  #pragma unroll
  for (int nd=0;nd<8;nd++){
    ob[(size_t)(q4*4 + 0)*K2 + nd*16 + lr] = f2bf(o[nd][0]*linv0);
    ob[(size_t)(q4*4 + 1)*K2 + nd*16 + lr] = f2bf(o[nd][1]*linv1);
    ob[(size_t)(q4*4 + 2)*K2 + nd*16 + lr] = f2bf(o[nd][2]*linv2);
    ob[(size_t)(q4*4 + 3)*K2 + nd*16 + lr] = f2bf(o[nd][3]*linv3);
  }
}

// ---------------- SwiGLU (out has row stride K2, at col offset DIM) ----------------
__global__ __launch_bounds__(256) void swiglu_kernel(const uint16_t* __restrict__ qkv,
                                                     uint16_t* __restrict__ mlp){
  size_t idx = ((size_t)blockIdx.x*256 + threadIdx.x)*4;
  size_t s = idx/MLP, j = idx - s*MLP;
  const uint16_t* pa = qkv + s*SD + 3*DIM + j;
  const uint16_t* pb = pa + MLP;
  ushort4 ua = *(const ushort4*)pa, ub = *(const ushort4*)pb;
  ushort4 o;
  float a, b;
  a = bf2f(ua.x); b = bf2f(ub.x); o.x = f2bf(a*b/(1.f+__expf(-a)));
  a = bf2f(ua.y); b = bf2f(ub.y); o.y = f2bf(a*b/(1.f+__expf(-a)));
  a = bf2f(ua.z); b = bf2f(ub.z); o.z = f2bf(a*b/(1.f+__expf(-a)));
  a = bf2f(ua.w); b = bf2f(ub.w); o.w = f2bf(a*b/(1.f+__expf(-a)));
  *(ushort4*)(mlp + s*K2 + j) = o;
}

extern "C" void kernel_launch(void* const* d_in, const int* in_sizes, int n_in,
                              void* d_out, int out_size, void* d_ws, size_t ws_size,
                              hipStream_t stream){
  (void)in_sizes; (void)n_in; (void)out_size;
  const float* hs   = (const float*)d_in[0];
  const float* temb = (const float*)d_in[1];
  const float* rcos = (const float*)d_in[2];
  const float* rsin = (const float*)d_in[3];
  const float* w1   = (const float*)d_in[4];
  const float* wa   = (const float*)d_in[5];
  const float* wm   = (const float*)d_in[6];
  const float* nqw  = (const float*)d_in[7];
  const float* nkw  = (const float*)d_in[8];

  char* ws = (char*)d_ws;
  const size_t off_w1T  = 0;               // 27648x3072 bf16 = 169,869,312
  const size_t off_woT  = 169869312ULL;    // 3072x12288 bf16 =  75,497,472
  const size_t off_h    = 245366784ULL;    // 4096x3072  bf16 =  25,165,824
  const size_t off_qkv  = 270532608ULL;    // 4096x27648 bf16 = 226,492,416
  const size_t off_ap   = 497025024ULL;    // 4096x12288 bf16 = 100,663,296
  const size_t needed   = 597688320ULL;
  if (ws_size < needed) return;

  uint16_t* w1T  = (uint16_t*)(ws + off_w1T);
  uint16_t* woT  = (uint16_t*)(ws + off_woT);
  uint16_t* hbuf = (uint16_t*)(ws + off_h);
  uint16_t* qkv  = (uint16_t*)(ws + off_qkv);
  uint16_t* ap   = (uint16_t*)(ws + off_ap);   // [attn | swiglu] fused A'

  castT_kernel<<<dim3(FUSED/32, DIM/32), 256, 0, stream>>>(w1, w1T, DIM, FUSED, DIM);
  castT_kernel<<<dim3(DIM/32,  DIM/32),  256, 0, stream>>>(wa, woT, DIM, DIM, K2);
  castT_kernel<<<dim3(DIM/32,  MLP/32),  256, 0, stream>>>(wm, woT + DIM, MLP, DIM, K2);
  ln_mod_kernel<<<SEQ, 256, 0, stream>>>(hs, temb, hbuf);
  gemm256_kernel<true,false><<<(SEQ/256)*(FUSED/256), 512, 0, stream>>>(hbuf, w1T, qkv, nullptr, nullptr, SEQ, FUSED, DIM);
  qk_rope_kernel<<<SEQ*NH/4, 256, 0, stream>>>(qkv, rcos, rsin, nqw, nkw);
  attn_kernel<<<dim3(SEQ/64, NH), 256, 0, stream>>>(qkv, ap);
  swiglu_kernel<<<(SEQ*(size_t)MLP/4)/256, 256, 0, stream>>>(qkv, ap + DIM);
  gemm256_kernel<false,true><<<(SEQ/256)*(DIM/256), 512, 0, stream>>>(ap, woT, d_out, hs, temb, SEQ, DIM, K2);
}

// Round 6
// 2273.281 us; speedup vs baseline: 1.0764x; 1.0067x over previous
//
#include <hip/hip_runtime.h>
#include <stdint.h>
#include <math.h>

#define DIM 3072
#define SEQ 4096
#define NH 24
#define HD 128
#define MLP 9216
#define FUSED 27648   // 3*DIM + 2*MLP
#define SD FUSED      // row stride of qkv_mlp buffer
#define K2 12288      // fused output-GEMM K (DIM + MLP)

typedef __attribute__((ext_vector_type(8))) short short8;
typedef __attribute__((ext_vector_type(4))) float f32x4;

__device__ __forceinline__ float bf2f(uint16_t b){ uint32_t x = ((uint32_t)b)<<16; return __builtin_bit_cast(float,x); }
__device__ __forceinline__ uint16_t f2bf(float f){
  uint32_t x = __builtin_bit_cast(uint32_t,f);
  x += 0x7fffu + ((x>>16)&1u);
  return (uint16_t)(x>>16);
}
__device__ __forceinline__ void gl_lds16(const void* g, void* l){
  __builtin_amdgcn_global_load_lds((const __attribute__((address_space(1))) void*)g,
                                   (__attribute__((address_space(3))) void*)l, 16, 0, 0);
}

// ---------------- transpose + cast fp32[K,N] -> bf16[N,:] at dst[n*dstStride + k] ----------------
__global__ __launch_bounds__(256) void castT_kernel(const float* __restrict__ src,
                                                    uint16_t* __restrict__ dst,
                                                    int K, int N, int dstStride){
  __shared__ float tile[32][33];
  int t = threadIdx.x;
  int n0 = blockIdx.x<<5, k0 = blockIdx.y<<5;
  int r = t>>3, c4 = (t&7)<<2;
  float4 v = *(const float4*)&src[(size_t)(k0+r)*N + n0 + c4];
  tile[r][c4] = v.x; tile[r][c4+1] = v.y; tile[r][c4+2] = v.z; tile[r][c4+3] = v.w;
  __syncthreads();
  int n = t>>3, kc = (t&7)<<2;
  ushort4 o;
  o.x = f2bf(tile[kc  ][n]);
  o.y = f2bf(tile[kc+1][n]);
  o.z = f2bf(tile[kc+2][n]);
  o.w = f2bf(tile[kc+3][n]);
  *(ushort4*)&dst[(size_t)(n0+n)*dstStride + k0 + kc] = o;
}

// ---------------- LayerNorm + modulation -> bf16 h ----------------
__global__ __launch_bounds__(256) void ln_mod_kernel(const float* __restrict__ x,
                                                     const float* __restrict__ temb,
                                                     uint16_t* __restrict__ h){
  int s = blockIdx.x;
  int t = threadIdx.x;
  const float4* row = (const float4*)(x + (size_t)s*DIM);
  float4 v[3];
  float sum=0.f, ss=0.f;
  #pragma unroll
  for (int i=0;i<3;i++){
    v[i] = row[t + i*256];
    sum += v[i].x+v[i].y+v[i].z+v[i].w;
    ss  += v[i].x*v[i].x + v[i].y*v[i].y + v[i].z*v[i].z + v[i].w*v[i].w;
  }
  #pragma unroll
  for (int off=32; off; off>>=1){ sum += __shfl_xor(sum, off, 64); ss += __shfl_xor(ss, off, 64); }
  __shared__ float red[8];
  int lane = t&63, w = t>>6;
  if (lane==0){ red[w]=sum; red[w+4]=ss; }
  __syncthreads();
  sum = red[0]+red[1]+red[2]+red[3];
  ss  = red[4]+red[5]+red[6]+red[7];
  float mu = sum*(1.f/DIM);
  float var = ss*(1.f/DIM) - mu*mu;
  float rs = rsqrtf(var + 1e-6f);
  uint16_t* hrow = h + (size_t)s*DIM;
  #pragma unroll
  for (int i=0;i<3;i++){
    int c = (t + i*256)*4;
    float4 sc = *(const float4*)&temb[DIM + c];
    float4 sh = *(const float4*)&temb[c];
    ushort4 o;
    o.x = f2bf((v[i].x - mu)*rs*(1.f+sc.x) + sh.x);
    o.y = f2bf((v[i].y - mu)*rs*(1.f+sc.y) + sh.y);
    o.z = f2bf((v[i].z - mu)*rs*(1.f+sc.z) + sh.z);
    o.w = f2bf((v[i].w - mu)*rs*(1.f+sc.w) + sh.w);
    *(ushort4*)&hrow[c] = o;
  }
}

// ---------------- 256x256-tile 8-phase GEMM (round-1 verified best: 762us GEMM1) ----------------
#define STAGE_HT(SRC, LDSB, KOFF) do{ \
    gl_lds16((SRC) + (KOFF), (LDSB) + (size_t)t*8); \
    gl_lds16((SRC) + r64K + (KOFF), (LDSB) + (size_t)(t+512)*8); \
  }while(0)

#define GPHASE(MI0, MI1, STG, WAITV) do{ \
    short8 a00 = *(const short8*)&Ab[(MI0)*1024 + pk0]; \
    short8 a01 = *(const short8*)&Ab[(MI0)*1024 + pk1]; \
    short8 a10 = *(const short8*)&Ab[(MI1)*1024 + pk0]; \
    short8 a11 = *(const short8*)&Ab[(MI1)*1024 + pk1]; \
    STG; \
    __builtin_amdgcn_s_barrier(); \
    asm volatile("s_waitcnt lgkmcnt(0)" ::: "memory"); \
    __builtin_amdgcn_s_setprio(1); \
    _Pragma("unroll") \
    for (int ni=0; ni<4; ni++){ \
      acc[MI0][ni] = __builtin_amdgcn_mfma_f32_16x16x32_bf16(a00, bfr[ni][0], acc[MI0][ni], 0,0,0); \
      acc[MI1][ni] = __builtin_amdgcn_mfma_f32_16x16x32_bf16(a10, bfr[ni][0], acc[MI1][ni], 0,0,0); \
      acc[MI0][ni] = __builtin_amdgcn_mfma_f32_16x16x32_bf16(a01, bfr[ni][1], acc[MI0][ni], 0,0,0); \
      acc[MI1][ni] = __builtin_amdgcn_mfma_f32_16x16x32_bf16(a11, bfr[ni][1], acc[MI1][ni], 0,0,0); \
    } \
    __builtin_amdgcn_s_setprio(0); \
    WAITV \
    __builtin_amdgcn_s_barrier(); \
  }while(0)

template<bool OUT_BF16, bool FINAL>
__global__ __launch_bounds__(512,2) void gemm256_kernel(const uint16_t* __restrict__ A,
                                                        const uint16_t* __restrict__ BT,
                                                        void* __restrict__ Cout,
                                                        const float* __restrict__ resid,
                                                        const float* __restrict__ temb,
                                                        int M, int N, int K){
  __shared__ alignas(16) uint16_t As[2][2][128*64];
  __shared__ alignas(16) uint16_t Bs[2][2][128*64];
  const int t = threadIdx.x, lane = t&63, w = t>>6;
  const int G = gridDim.x, cpx = G>>3;
  const int b = blockIdx.x;
  const int b2 = (b&7)*cpx + (b>>3);
  const int mt = M>>8;
  const int n_t = b2/mt, m_t = b2 - n_t*mt;
  const size_t m0 = (size_t)m_t<<8, n0 = (size_t)n_t<<8;
  const int wm = (w>>2)<<7, wn = (w&3)<<6;
  const int lr = lane&15, q4 = lane>>4;
  const int r0 = t>>3;
  const int g0 = (t&7) ^ (r0&7);
  const uint16_t* Asrc = A  + (m0 + r0)*(size_t)K + g0*8;
  const uint16_t* Bsrc = BT + (n0 + r0)*(size_t)K + g0*8;
  const size_t r64K = (size_t)64*K, r128K = (size_t)128*K;
  const int halfA = w>>2, halfB = (w&3)>>1, rbB = wn&64;
  const uint16_t* ArdBase = &As[0][halfA][0] + lr*64;
  const uint16_t* BrdBase = &Bs[0][halfB][0] + (rbB+lr)*64;
  const int x7 = lr&7;
  const int pk0 = (q4^x7)<<3, pk1 = ((q4|4)^x7)<<3;
  // prologue: T0 fully (8 loads) + T1.B halves (4 loads); vmcnt(4) drains T0 only
  STAGE_HT(Bsrc, &Bs[0][0][0], (size_t)0);
  STAGE_HT(Bsrc, &Bs[0][1][0], r128K);
  STAGE_HT(Asrc, &As[0][0][0], (size_t)0);
  STAGE_HT(Asrc, &As[0][1][0], r128K);
  STAGE_HT(Bsrc, &Bs[1][0][0], (size_t)64);
  STAGE_HT(Bsrc, &Bs[1][1][0], r128K + 64);
  asm volatile("s_waitcnt vmcnt(4)" ::: "memory");
  __builtin_amdgcn_s_barrier();
  f32x4 acc[8][4] = {};
  const int NT = K>>6;
  for (int T=0; T<NT; ++T){
    const int cur = T&1, nxt = cur^1;
    const uint16_t* Ab = ArdBase + (cur<<14);
    const uint16_t* Bb = BrdBase + (cur<<14);
    uint16_t* AsN0 = &As[nxt][0][0]; uint16_t* AsN1 = &As[nxt][1][0];
    uint16_t* BsC0 = &Bs[cur][0][0]; uint16_t* BsC1 = &Bs[cur][1][0];
    const bool stA = (T+1<NT), stB = (T+2<NT);
    const size_t kA = (size_t)(T+1)<<6, kB = (size_t)(T+2)<<6;
    short8 bfr[4][2];
    #pragma unroll
    for (int ni=0; ni<4; ni++){
      bfr[ni][0] = *(const short8*)&Bb[ni*1024 + pk0];
      bfr[ni][1] = *(const short8*)&Bb[ni*1024 + pk1];
    }
    GPHASE(0,1, if(stA){ STAGE_HT(Asrc, AsN0, kA); }, ;);
    GPHASE(2,3, if(stA){ STAGE_HT(Asrc, AsN1, kA + r128K); }, ;);
    GPHASE(4,5, if(stB){ STAGE_HT(Bsrc, BsC0, kB); }, ;);
    GPHASE(6,7, if(stB){ STAGE_HT(Bsrc, BsC1, kB + r128K); },
           if(stB){ asm volatile("s_waitcnt vmcnt(4)" ::: "memory"); }
           else   { asm volatile("s_waitcnt vmcnt(0)" ::: "memory"); });
  }
  #pragma unroll
  for (int mi=0; mi<8; mi++){
    #pragma unroll
    for (int ni=0; ni<4; ni++){
      const size_t col = n0 + wn + ni*16 + lr;
      const float gate = FINAL ? temb[2*DIM + col] : 0.f;
      #pragma unroll
      for (int r=0; r<4; r++){
        const size_t row = m0 + wm + mi*16 + (q4<<2) + r;
        const size_t idx = row*(size_t)N + col;
        float vv = acc[mi][ni][r];
        if (FINAL) vv = resid[idx] + gate*vv;
        if (OUT_BF16) ((uint16_t*)Cout)[idx] = f2bf(vv);
        else          ((float*)Cout)[idx] = vv;
      }
    }
  }
}

// ---------------- per-head RMSNorm + RoPE on q,k (in place) ----------------
__global__ __launch_bounds__(256) void qk_rope_kernel(uint16_t* __restrict__ qkv,
                                                      const float* __restrict__ cosb,
                                                      const float* __restrict__ sinb,
                                                      const float* __restrict__ wq,
                                                      const float* __restrict__ wk){
  int t = threadIdx.x, lane = t&63, w = t>>6;
  int pair = blockIdx.x*4 + w;
  int s = pair/24, hh = pair - s*24;
  int d0 = lane*2;
  float c0 = cosb[s*HD + d0], c1 = cosb[s*HD + d0+1];
  float sn0 = sinb[s*HD + d0], sn1 = sinb[s*HD + d0+1];
  #pragma unroll
  for (int which=0; which<2; ++which){
    uint16_t* p = qkv + (size_t)s*SD + which*DIM + hh*HD + d0;
    const float* ww = which ? wk : wq;
    uint32_t u = *(const uint32_t*)p;
    float x0 = bf2f((uint16_t)(u&0xffffu)), x1 = bf2f((uint16_t)(u>>16));
    float ssum = x0*x0 + x1*x1;
    #pragma unroll
    for (int off=32; off; off>>=1) ssum += __shfl_xor(ssum, off, 64);
    float r = rsqrtf(ssum*(1.f/HD) + 1e-6f);
    float xn0 = x0*r*ww[d0], xn1 = x1*r*ww[d0+1];
    float y0 = xn0*c0 - xn1*sn0;
    float y1 = xn1*c1 + xn0*sn1;
    *(uint32_t*)p = (uint32_t)f2bf(y0) | ((uint32_t)f2bf(y1)<<16);
  }
}

// ---------------- flash attention v2: double-buffered K/V, 1 barrier/tile ----------------
// Swapped QK^T (S^T = mfma(K,Q), scores lane-local), packed P-store, defer-max (T13).
// T14 async-stage: tile t+1's K (global_load_lds, pre-swizzled source) and V (16 reg
// loads) are ISSUED before tile t's compute; after PV, vmcnt(0) (free — issued ~2500cy
// earlier) then V transpose-written to Vt[nxt]; ONE __syncthreads per tile.
// Buffer safety: [nxt] was last read in tile t-1, those reads completed before that
// tile's barrier; stage-writes drain before this wave's barrier arrival.
__global__ __launch_bounds__(256) void attn_kernel(const uint16_t* __restrict__ qkv,
                                                   uint16_t* __restrict__ out){
  __shared__ alignas(16) uint16_t QP[64*128];      // Q staging, then per-wave P (swizzled)
  __shared__ alignas(16) uint16_t Ks[2][64*128];   // [key][d], d-granule swizzled by key&15
  __shared__ alignas(16) uint16_t Vt[2][128*64];   // [d][key], key-granule swizzled
  int t = threadIdx.x, lane = t&63, w = t>>6;
  int q0 = blockIdx.x<<6, h = blockIdx.y;
  int lr = lane&15, q4 = lane>>4, lk = q4<<3;
  const uint16_t* qb = qkv + (size_t)q0*SD + h*HD;
  const uint16_t* kb = qkv + (size_t)DIM + h*HD;
  const uint16_t* vb = qkv + (size_t)(2*DIM) + h*HD;
  #pragma unroll
  for (int i=0;i<4;i++){
    int c = t + i*256;
    gl_lds16((const char*)(qb + (size_t)(c>>4)*SD) + ((c&15)<<4), (char*)QP + c*16);
  }
  // stage K0 (pre-swizzled source -> linear LDS dest)
  #pragma unroll
  for (int i=0;i<4;i++){
    int c = t + i*256;
    int row = c>>4, gd = c&15;
    gl_lds16((const char*)(kb + (size_t)row*SD) + (((gd ^ (row&15))&15)<<4),
             (char*)Ks[0] + c*16);
  }
  // load V0 into regs
  uint32_t vr0[8], vr1[8];
  #pragma unroll
  for (int i=0;i<8;i++){
    int rp = w + i*4;
    int k0 = rp<<1, d0 = lane<<1;
    vr0[i] = *(const uint32_t*)(vb + (size_t)k0*SD + d0);
    vr1[i] = *(const uint32_t*)(vb + (size_t)(k0+1)*SD + d0);
  }
  __syncthreads();   // Q + K0 staged (barrier drains each wave's vmcnt)
  short8 qf[4];
  #pragma unroll
  for (int kc=0;kc<4;kc++) qf[kc] = *(const short8*)&QP[(w*16+lr)*128 + kc*32 + lk];
  // transpose-write V0 -> Vt[0]
  #pragma unroll
  for (int i=0;i<8;i++){
    int rp = w + i*4;
    int k0 = rp<<1, d0 = lane<<1;
    int pos = (((rp>>2) ^ (lane&7))<<3) + (k0&7);
    *(uint32_t*)&Vt[0][(d0<<6) + pos]     = (vr0[i]&0xffffu) | (vr1[i]<<16);
    *(uint32_t*)&Vt[0][((d0+1)<<6) + pos] = (vr0[i]>>16) | (vr1[i]&0xffff0000u);
  }
  __syncthreads();   // QP now P scratch; Vt[0] visible
  float m_q = -3.0e38f, l_q = 0.f;   // running max/denom for query q=lr (replicated x4)
  f32x4 o[8] = {};
  uint16_t* Pw = QP + w*(16*64);
  const float scale = 0.08838834764831845f;
  for (int kt=0; kt<64; ++kt){
    const int cur = kt&1, nxt = cur^1;
    const bool more = (kt+1 < 64);
    if (more){
      const uint16_t* kbt = kb + (size_t)((kt+1)<<6)*SD;
      const uint16_t* vbt = vb + (size_t)((kt+1)<<6)*SD;
      #pragma unroll
      for (int i=0;i<4;i++){
        int c = t + i*256;
        int row = c>>4, gd = c&15;
        gl_lds16((const char*)(kbt + (size_t)row*SD) + (((gd ^ (row&15))&15)<<4),
                 (char*)Ks[nxt] + c*16);
      }
      #pragma unroll
      for (int i=0;i<8;i++){
        int rp = w + i*4;
        int k0 = rp<<1, d0 = lane<<1;
        vr0[i] = *(const uint32_t*)(vbt + (size_t)k0*SD + d0);
        vr1[i] = *(const uint32_t*)(vbt + (size_t)(k0+1)*SD + d0);
      }
    }
    // QK^T swapped: ta[nk][r] = S[q=lr][key = nk*16 + q4*4 + r] * scale
    f32x4 ta[4];
    __builtin_amdgcn_s_setprio(1);
    #pragma unroll
    for (int nk=0;nk<4;nk++){
      ta[nk] = (f32x4){0.f,0.f,0.f,0.f};
      #pragma unroll
      for (int kc=0;kc<4;kc++){
        short8 kf = *(const short8*)&Ks[cur][(nk*16+lr)*128 + (((kc*4+q4) ^ lr)<<3)];
        ta[nk] = __builtin_amdgcn_mfma_f32_16x16x32_bf16(kf, qf[kc], ta[nk], 0,0,0);
      }
      ta[nk] *= scale;
    }
    __builtin_amdgcn_s_setprio(0);
    // in-lane max over 16 + 2 shfl across q4 groups
    float mx01 = fmaxf(fmaxf(ta[0][0],ta[0][1]), fmaxf(ta[0][2],ta[0][3]));
    float mx23 = fmaxf(fmaxf(ta[1][0],ta[1][1]), fmaxf(ta[1][2],ta[1][3]));
    float mx45 = fmaxf(fmaxf(ta[2][0],ta[2][1]), fmaxf(ta[2][2],ta[2][3]));
    float mx67 = fmaxf(fmaxf(ta[3][0],ta[3][1]), fmaxf(ta[3][2],ta[3][3]));
    float pmax = fmaxf(fmaxf(mx01,mx23), fmaxf(mx45,mx67));
    pmax = fmaxf(pmax, __shfl_xor(pmax, 16, 64));
    pmax = fmaxf(pmax, __shfl_xor(pmax, 32, 64));
    // defer-max: keep old m if no significant growth (wave-uniform)
    int skip = __all(pmax <= m_q + 8.f);
    float alpha_q = 1.f;
    if (!skip){
      float mnew = fmaxf(m_q, pmax);
      alpha_q = __expf(m_q - mnew);
      m_q = mnew;
    }
    float psum = 0.f;
    #pragma unroll
    for (int nk=0;nk<4;nk++){
      float p0 = __expf(ta[nk][0] - m_q);
      float p1 = __expf(ta[nk][1] - m_q);
      float p2 = __expf(ta[nk][2] - m_q);
      float p3 = __expf(ta[nk][3] - m_q);
      psum += (p0+p1)+(p2+p3);
      uint32_t lo = (uint32_t)f2bf(p0) | ((uint32_t)f2bf(p1)<<16);
      uint32_t hi = (uint32_t)f2bf(p2) | ((uint32_t)f2bf(p3)<<16);
      int k0 = nk*16 + (q4<<2);
      uint2 pk; pk.x = lo; pk.y = hi;
      *(uint2*)&Pw[lr*64 + ((((k0>>3) ^ lr)&7)<<3) + (k0&7)] = pk;
    }
    psum += __shfl_xor(psum, 16, 64);
    psum += __shfl_xor(psum, 32, 64);
    l_q = l_q*alpha_q + psum;
    if (!skip){
      float aR0 = __shfl(alpha_q, (q4<<2)+0, 64);
      float aR1 = __shfl(alpha_q, (q4<<2)+1, 64);
      float aR2 = __shfl(alpha_q, (q4<<2)+2, 64);
      float aR3 = __shfl(alpha_q, (q4<<2)+3, 64);
      #pragma unroll
      for (int nd=0;nd<8;nd++){
        f32x4 t4 = o[nd];
        t4[0]*=aR0; t4[1]*=aR1; t4[2]*=aR2; t4[3]*=aR3;
        o[nd]=t4;
      }
    }
    __builtin_amdgcn_s_setprio(1);
    #pragma unroll
    for (int kc=0;kc<2;kc++){
      short8 pf = *(const short8*)&Pw[lr*64 + ((((kc*4+q4) ^ lr)&7)<<3)];
      #pragma unroll
      for (int nd=0;nd<8;nd++){
        int d = nd*16 + lr;
        short8 vf = *(const short8*)&Vt[cur][(d<<6) + ((((kc*4+q4) ^ ((lr>>1)&7)))<<3)];
        o[nd] = __builtin_amdgcn_mfma_f32_16x16x32_bf16(pf, vf, o[nd], 0,0,0);
      }
    }
    __builtin_amdgcn_s_setprio(0);
    if (more){
      asm volatile("s_waitcnt vmcnt(0)" ::: "memory");   // K gl_lds + V reg loads landed
      #pragma unroll
      for (int i=0;i<8;i++){
        int rp = w + i*4;
        int k0 = rp<<1, d0 = lane<<1;
        int pos = (((rp>>2) ^ (lane&7))<<3) + (k0&7);
        *(uint32_t*)&Vt[nxt][(d0<<6) + pos]     = (vr0[i]&0xffffu) | (vr1[i]<<16);
        *(uint32_t*)&Vt[nxt][((d0+1)<<6) + pos] = (vr0[i]>>16) | (vr1[i]&0xffff0000u);
      }
    }
    __syncthreads();
  }
  float linv0 = 1.f/__shfl(l_q, (q4<<2)+0, 64);
  float linv1 = 1.f/__shfl(l_q, (q4<<2)+1, 64);
  float linv2 = 1.f/__shfl(l_q, (q4<<2)+2, 64);
  float linv3 = 1.f/__shfl(l_q, (q4<<2)+3, 64);
  uint16_t* ob = out + (size_t)(q0 + w*16)*K2 + h*HD;
  #pragma unroll
  for (int nd=0;nd<8;nd++){
    ob[(size_t)(q4*4 + 0)*K2 + nd*16 + lr] = f2bf(o[nd][0]*linv0);
    ob[(size_t)(q4*4 + 1)*K2 + nd*16 + lr] = f2bf(o[nd][1]*linv1);
    ob[(size_t)(q4*4 + 2)*K2 + nd*16 + lr] = f2bf(o[nd][2]*linv2);
    ob[(size_t)(q4*4 + 3)*K2 + nd*16 + lr] = f2bf(o[nd][3]*linv3);
  }
}

// ---------------- SwiGLU (out has row stride K2, at col offset DIM) ----------------
__global__ __launch_bounds__(256) void swiglu_kernel(const uint16_t* __restrict__ qkv,
                                                     uint16_t* __restrict__ mlp){
  size_t idx = ((size_t)blockIdx.x*256 + threadIdx.x)*4;
  size_t s = idx/MLP, j = idx - s*MLP;
  const uint16_t* pa = qkv + s*SD + 3*DIM + j;
  const uint16_t* pb = pa + MLP;
  ushort4 ua = *(const ushort4*)pa, ub = *(const ushort4*)pb;
  ushort4 o;
  float a, b;
  a = bf2f(ua.x); b = bf2f(ub.x); o.x = f2bf(a*b/(1.f+__expf(-a)));
  a = bf2f(ua.y); b = bf2f(ub.y); o.y = f2bf(a*b/(1.f+__expf(-a)));
  a = bf2f(ua.z); b = bf2f(ub.z); o.z = f2bf(a*b/(1.f+__expf(-a)));
  a = bf2f(ua.w); b = bf2f(ub.w); o.w = f2bf(a*b/(1.f+__expf(-a)));
  *(ushort4*)(mlp + s*K2 + j) = o;
}

extern "C" void kernel_launch(void* const* d_in, const int* in_sizes, int n_in,
                              void* d_out, int out_size, void* d_ws, size_t ws_size,
                              hipStream_t stream){
  (void)in_sizes; (void)n_in; (void)out_size;
  const float* hs   = (const float*)d_in[0];
  const float* temb = (const float*)d_in[1];
  const float* rcos = (const float*)d_in[2];
  const float* rsin = (const float*)d_in[3];
  const float* w1   = (const float*)d_in[4];
  const float* wa   = (const float*)d_in[5];
  const float* wm   = (const float*)d_in[6];
  const float* nqw  = (const float*)d_in[7];
  const float* nkw  = (const float*)d_in[8];

  char* ws = (char*)d_ws;
  const size_t off_w1T  = 0;               // 27648x3072 bf16 = 169,869,312
  const size_t off_woT  = 169869312ULL;    // 3072x12288 bf16 =  75,497,472
  const size_t off_h    = 245366784ULL;    // 4096x3072  bf16 =  25,165,824
  const size_t off_qkv  = 270532608ULL;    // 4096x27648 bf16 = 226,492,416
  const size_t off_ap   = 497025024ULL;    // 4096x12288 bf16 = 100,663,296
  const size_t needed   = 597688320ULL;
  if (ws_size < needed) return;

  uint16_t* w1T  = (uint16_t*)(ws + off_w1T);
  uint16_t* woT  = (uint16_t*)(ws + off_woT);
  uint16_t* hbuf = (uint16_t*)(ws + off_h);
  uint16_t* qkv  = (uint16_t*)(ws + off_qkv);
  uint16_t* ap   = (uint16_t*)(ws + off_ap);   // [attn | swiglu] fused A'

  castT_kernel<<<dim3(FUSED/32, DIM/32), 256, 0, stream>>>(w1, w1T, DIM, FUSED, DIM);
  castT_kernel<<<dim3(DIM/32,  DIM/32),  256, 0, stream>>>(wa, woT, DIM, DIM, K2);
  castT_kernel<<<dim3(DIM/32,  MLP/32),  256, 0, stream>>>(wm, woT + DIM, MLP, DIM, K2);
  ln_mod_kernel<<<SEQ, 256, 0, stream>>>(hs, temb, hbuf);
  gemm256_kernel<true,false><<<(SEQ/256)*(FUSED/256), 512, 0, stream>>>(hbuf, w1T, qkv, nullptr, nullptr, SEQ, FUSED, DIM);
  qk_rope_kernel<<<SEQ*NH/4, 256, 0, stream>>>(qkv, rcos, rsin, nqw, nkw);
  attn_kernel<<<dim3(SEQ/64, NH), 256, 0, stream>>>(qkv, ap);
  swiglu_kernel<<<(SEQ*(size_t)MLP/4)/256, 256, 0, stream>>>(qkv, ap + DIM);
  gemm256_kernel<false,true><<<(SEQ/256)*(DIM/256), 512, 0, stream>>>(ap, woT, d_out, hs, temb, SEQ, DIM, K2);
}